// Round 5
// baseline (670.414 us; speedup 1.0000x reference)
//
#include <hip/hip_runtime.h>
#include <math.h>

#define N_NODES  100000
#define N_EDGES  1600000
#define N_GRAPHS 1000
#define NPG      100
#define NB_SCAN  ((N_NODES + 255) / 256)   // 391

__device__ __forceinline__ float elu_f(float x) {
    return x > 0.0f ? x : expm1f(x);
}

// ---------------- CSR build ----------------
__global__ __launch_bounds__(256) void zero_cnt_k(int* __restrict__ cnt) {
    int i = blockIdx.x * 256 + threadIdx.x;
    if (i < N_NODES) cnt[i] = 0;
}

// 4 edges/thread: independent atomics -> 4x memory-level parallelism
__global__ __launch_bounds__(256) void count_k(const int* __restrict__ ei, int* __restrict__ cnt) {
    int e = (blockIdx.x * 256 + threadIdx.x) * 4;
    if (e + 4 <= N_EDGES) {
        int4 d = *(const int4*)(ei + N_EDGES + e);
        atomicAdd(&cnt[d.x], 1);
        atomicAdd(&cnt[d.y], 1);
        atomicAdd(&cnt[d.z], 1);
        atomicAdd(&cnt[d.w], 1);
    }
}

// 3-kernel device-wide exclusive scan over cnt
__global__ __launch_bounds__(256) void scan_bsum_k(const int* __restrict__ cnt, int* __restrict__ bsum) {
    __shared__ int red[256];
    int t = threadIdx.x;
    int i = blockIdx.x * 256 + t;
    red[t] = (i < N_NODES) ? cnt[i] : 0;
    __syncthreads();
    #pragma unroll
    for (int off = 128; off > 0; off >>= 1) {
        if (t < off) red[t] += red[t + off];
        __syncthreads();
    }
    if (t == 0) bsum[blockIdx.x] = red[0];
}

__global__ __launch_bounds__(512) void scan_boff_k(const int* __restrict__ bsum, int* __restrict__ boff) {
    __shared__ int s[512];
    int t = threadIdx.x;
    s[t] = (t < NB_SCAN) ? bsum[t] : 0;
    __syncthreads();
    #pragma unroll
    for (int off = 1; off < 512; off <<= 1) {
        int u = (t >= off) ? s[t - off] : 0;
        __syncthreads();
        s[t] += u;
        __syncthreads();
    }
    boff[t] = (t == 0) ? 0 : s[t - 1];
}

__global__ __launch_bounds__(256) void scan_apply_k(const int* __restrict__ cnt,
                                                    const int* __restrict__ boff,
                                                    int* __restrict__ starts,
                                                    int* __restrict__ cursor,
                                                    float* __restrict__ dis)
{
    __shared__ int s[256];
    int t = threadIdx.x;
    int i = blockIdx.x * 256 + t;
    int v = (i < N_NODES) ? cnt[i] : 0;
    s[t] = v;
    __syncthreads();
    #pragma unroll
    for (int off = 1; off < 256; off <<= 1) {
        int u = (t >= off) ? s[t - off] : 0;
        __syncthreads();
        s[t] += u;
        __syncthreads();
    }
    if (i < N_NODES) {
        int ex = boff[blockIdx.x] + s[t] - v;
        starts[i] = ex;
        cursor[i] = ex;
        dis[i] = rsqrtf(1.0f + (float)v);
    }
}

// 4 edges/thread: 4 independent atomic round-trips + stores in flight
__global__ __launch_bounds__(256) void fill_k(const int* __restrict__ ei,
                                              int* __restrict__ cursor,
                                              int* __restrict__ srclist)
{
    int e = (blockIdx.x * 256 + threadIdx.x) * 4;
    if (e + 4 <= N_EDGES) {
        int4 s = *(const int4*)(ei + e);
        int4 d = *(const int4*)(ei + N_EDGES + e);
        int p0 = atomicAdd(&cursor[d.x], 1);
        int p1 = atomicAdd(&cursor[d.y], 1);
        int p2 = atomicAdd(&cursor[d.z], 1);
        int p3 = atomicAdd(&cursor[d.w], 1);
        srclist[p0] = s.x;
        srclist[p1] = s.y;
        srclist[p2] = s.z;
        srclist[p3] = s.w;
    }
}

// ---------------- generic node GEMM: C = post(A[M,K] @ W[N,K]^T) ----------------
template<int K, int N, int NT, int TN, int TC, bool ELU, bool SCALE, bool BIAS>
__global__ __launch_bounds__(256) void gemm_k(
    const float* __restrict__ A, const float* __restrict__ W,
    const float* __restrict__ bias, const float* __restrict__ dis,
    float* __restrict__ C, int M)
{
    constexpr int CG = N / TC;
    static_assert((NT / TN) * CG == 256, "thread mapping");
    constexpr int KP = K + 4;
    constexpr int NP = N + 4;

    __shared__ float Xs[NT * KP];
    __shared__ float Ws[K * NP];

    const int t = threadIdx.x;
    const int node0 = blockIdx.x * NT;

    for (int idx = t; idx < N * K; idx += 256) {
        int j = idx / K, k = idx % K;
        Ws[k * NP + j] = W[idx];
    }
    for (int idx = t; idx < NT * K; idx += 256) {
        int n = idx / K, k = idx % K;
        int gn = node0 + n;
        Xs[n * KP + k] = (gn < M) ? A[(size_t)gn * K + k] : 0.0f;
    }
    __syncthreads();

    const int ng = t / CG;
    const int cg = t % CG;

    float acc[TN][TC];
    #pragma unroll
    for (int i = 0; i < TN; ++i)
        #pragma unroll
        for (int j = 0; j < TC; ++j) acc[i][j] = 0.0f;

    #pragma unroll 4
    for (int k = 0; k < K; ++k) {
        float xv[TN];
        #pragma unroll
        for (int i = 0; i < TN; ++i) xv[i] = Xs[(ng * TN + i) * KP + k];
        const float* wr = &Ws[k * NP + cg * TC];
        float wv[TC];
        if constexpr (TC % 4 == 0) {
            #pragma unroll
            for (int j4 = 0; j4 < TC / 4; ++j4) {
                float4 v = *(const float4*)(wr + 4 * j4);
                wv[4*j4+0] = v.x; wv[4*j4+1] = v.y; wv[4*j4+2] = v.z; wv[4*j4+3] = v.w;
            }
        } else {
            float2 v = *(const float2*)wr;
            wv[0] = v.x; wv[1] = v.y;
        }
        #pragma unroll
        for (int j = 0; j < TC; ++j)
            #pragma unroll
            for (int i = 0; i < TN; ++i)
                acc[i][j] = fmaf(xv[i], wv[j], acc[i][j]);
    }

    #pragma unroll
    for (int i = 0; i < TN; ++i) {
        int gn = node0 + ng * TN + i;
        if (gn >= M) continue;
        float scale = 1.0f;
        if constexpr (SCALE) scale = dis[gn];
        #pragma unroll
        for (int j = 0; j < TC; ++j) {
            float v = acc[i][j];
            if constexpr (BIAS) v += bias[cg * TC + j];
            if constexpr (ELU)  v = elu_f(v);
            if constexpr (SCALE) v *= scale;
            C[(size_t)gn * N + cg * TC + j] = v;
        }
    }
}

// ---------------- layer-1 gather + combine + elu (divergence-safe, no shfl) ----------------
// block = 256 = 16 nodes x 16 threads; thread owns 4 features (float4) of c (64 feats)
__global__ __launch_bounds__(256) void gather1_k(
    const int* __restrict__ starts, const int* __restrict__ cnt,
    const int* __restrict__ srclist, const float* __restrict__ c,
    const float* __restrict__ w1, const float* __restrict__ dis,
    const float* __restrict__ bias, float* __restrict__ h2)
{
    __shared__ float aggS[16][68];
    __shared__ float w1S[16][32];

    const int t = threadIdx.x;
    const int nn = t >> 4;            // node within block
    const int q  = t & 15;            // feature quad
    const int n  = blockIdx.x * 16 + nn;

    // stage w1 tile (coalesced): 16 nodes x 32 floats = 512
    {
        int i0 = t * 2;
        int wn = i0 >> 5, wj = i0 & 31;
        float2 v = *(const float2*)(w1 + (size_t)(blockIdx.x * 16 + wn) * 32 + wj);
        w1S[wn][wj] = v.x;
        w1S[wn][wj + 1] = v.y;
    }

    const int s0 = starts[n];
    const int cn = cnt[n];
    float4 a = *(const float4*)(c + (size_t)n * 64 + q * 4);   // self term
    for (int j = 0; j < cn; ++j) {
        int src = srclist[s0 + j];                              // broadcast within group
        float4 v = *(const float4*)(c + (size_t)src * 64 + q * 4);
        a.x += v.x; a.y += v.y; a.z += v.z; a.w += v.w;
    }
    aggS[nn][q * 4 + 0] = a.x;
    aggS[nn][q * 4 + 1] = a.y;
    aggS[nn][q * 4 + 2] = a.z;
    aggS[nn][q * 4 + 3] = a.w;
    __syncthreads();

    // combine: thread (nn,q) computes outputs j = r*16 + q for r = 0..7 (f = q)
    float ab[4];
    #pragma unroll
    for (int b = 0; b < 4; ++b) ab[b] = aggS[nn][b * 16 + q];
    const float dn = dis[n];
    float* out = h2 + (size_t)n * 128;
    #pragma unroll
    for (int r = 0; r < 8; ++r) {
        float s = 0.0f;
        #pragma unroll
        for (int b = 0; b < 4; ++b) s = fmaf(w1S[nn][r * 4 + b], ab[b], s);
        out[r * 16 + q] = elu_f(s * dn + bias[r * 16 + q]);
    }
}

// ---------------- layer-2 gather + combine + elu + L2 normalize (divergence-safe) ----------------
// block = 256 = 8 nodes x 32 threads; thread owns 1 feature of c (32 feats)
__global__ __launch_bounds__(256) void gather2_k(
    const int* __restrict__ starts, const int* __restrict__ cnt,
    const int* __restrict__ srclist, const float* __restrict__ c,
    const float* __restrict__ w2, const float* __restrict__ dis,
    const float* __restrict__ bias, float* __restrict__ hout)
{
    __shared__ float aggS[8][36];
    __shared__ float w2S[8][32];

    const int t = threadIdx.x;
    const int nn = t >> 5;            // node within block
    const int q  = t & 31;            // feature
    const int n  = blockIdx.x * 8 + nn;

    // stage w2 tile (coalesced): 8 nodes x 32 floats = 256
    w2S[t >> 5][t & 31] = w2[(size_t)(blockIdx.x * 8 + (t >> 5)) * 32 + (t & 31)];

    const int s0 = starts[n];
    const int cn = cnt[n];
    float a = c[(size_t)n * 32 + q];                            // self term
    for (int j = 0; j < cn; ++j) {
        int src = srclist[s0 + j];
        a += c[(size_t)src * 32 + q];
    }
    aggS[nn][q] = a;
    __syncthreads();

    // combine: thread (nn,q) computes outputs j1 = q, j2 = q + 32
    const int f  = q & 7;
    const int hh = q >> 3;
    float ab[4];
    #pragma unroll
    for (int b = 0; b < 4; ++b) ab[b] = aggS[nn][b * 8 + f];
    const float dn = dis[n];
    float s1 = 0.0f, s2 = 0.0f;
    #pragma unroll
    for (int b = 0; b < 4; ++b) {
        s1 = fmaf(w2S[nn][hh * 4 + b], ab[b], s1);
        s2 = fmaf(w2S[nn][(hh + 4) * 4 + b], ab[b], s2);
    }
    s1 = elu_f(s1 * dn + bias[q]);
    s2 = elu_f(s2 * dn + bias[q + 32]);

    // L2 norm across the node's 64 outputs: reduce s1^2+s2^2 over the aligned 32-thread group
    float tot = s1 * s1 + s2 * s2;
    #pragma unroll
    for (int o = 1; o < 32; o <<= 1) tot += __shfl_xor(tot, o, 64);
    float inv = 1.0f / fmaxf(sqrtf(tot), 1e-12f);
    hout[(size_t)n * 64 + q]      = s1 * inv;
    hout[(size_t)n * 64 + 32 + q] = s2 * inv;
}

// ---------------- per-graph tail: z_a, attention softmax, z_c ----------------
__global__ __launch_bounds__(128) void graph_k(const float* __restrict__ h,
                                               const float* __restrict__ z_e,
                                               const float* __restrict__ aw,
                                               const float* __restrict__ ab,
                                               const float* __restrict__ fcgw,
                                               const float* __restrict__ fcgb,
                                               const float* __restrict__ fccgw,
                                               const float* __restrict__ fccgb,
                                               float* __restrict__ z_a,
                                               float* __restrict__ z_c)
{
    __shared__ float Hs[NPG * 64];
    __shared__ float sumh[64], wsh[64], lg[NPG], ex[NPG];
    __shared__ float red[2];
    int g = blockIdx.x, t = threadIdx.x;
    const float* hg = h + (size_t)g * NPG * 64;
    for (int idx = t; idx < NPG * 64; idx += 128) Hs[idx] = hg[idx];
    __syncthreads();

    if (t < 64) {
        float s = 0.0f;
        for (int n = 0; n < NPG; ++n) s += Hs[n * 64 + t];
        sumh[t] = s;
    }
    __syncthreads();

    if (t < 64) {
        float acc = fcgb[t];
        for (int f = 0; f < 64; ++f) acc = fmaf(sumh[f], fcgw[t * 64 + f], acc);
        z_a[(size_t)g * 64 + t] = acc;
    }
    if (t < NPG) {
        float zd = 0.0f;
        for (int q = 0; q < 32; ++q) zd = fmaf(z_e[(size_t)g * 32 + q], aw[64 + q], zd);
        float dot = 0.0f;
        for (int k0 = 0; k0 < 64; ++k0) {
            int k = (k0 + t) & 63;
            dot = fmaf(Hs[t * 64 + k], aw[k], dot);
        }
        lg[t] = dot + zd + ab[0] + 1e-16f;
    }
    __syncthreads();

    if (t < 64) {
        float m = -INFINITY;
        for (int n = t; n < NPG; n += 64) m = fmaxf(m, lg[n]);
        #pragma unroll
        for (int o = 1; o < 64; o <<= 1) m = fmaxf(m, __shfl_xor(m, o, 64));
        if (t == 0) red[0] = m;
    }
    __syncthreads();
    float m = red[0];
    if (t < NPG) ex[t] = expf(lg[t] - m);
    __syncthreads();
    if (t < 64) {
        float s = 0.0f;
        for (int n = t; n < NPG; n += 64) s += ex[n];
        #pragma unroll
        for (int o = 1; o < 64; o <<= 1) s += __shfl_xor(s, o, 64);
        if (t == 0) red[1] = s + 1e-16f;
    }
    __syncthreads();
    float inv_denom = 1.0f / red[1];
    if (t < 64) {
        float a = 0.0f;
        for (int n = 0; n < NPG; ++n) a = fmaf(ex[n], Hs[n * 64 + t], a);
        wsh[t] = a * inv_denom;
    }
    __syncthreads();
    if (t < 64) {
        float acc = fccgb[t];
        for (int f = 0; f < 64; ++f) acc = fmaf(wsh[f], fccgw[t * 64 + f], acc);
        z_c[(size_t)g * 64 + t] = acc;
    }
}

extern "C" void kernel_launch(void* const* d_in, const int* in_sizes, int n_in,
                              void* d_out, int out_size, void* d_ws, size_t ws_size,
                              hipStream_t stream)
{
    const float* x     = (const float*)d_in[0];
    const int*   ei    = (const int*)d_in[1];
    const float* z_e   = (const float*)d_in[4];
    const float* nfc_w = (const float*)d_in[5];
    const float* nfc_b = (const float*)d_in[6];
    const float* g1bw  = (const float*)d_in[7];
    const float* g1cw  = (const float*)d_in[8];
    const float* g1cb  = (const float*)d_in[9];
    const float* g1b   = (const float*)d_in[10];
    const float* g2bw  = (const float*)d_in[11];
    const float* g2cw  = (const float*)d_in[12];
    const float* g2cb  = (const float*)d_in[13];
    const float* g2b   = (const float*)d_in[14];
    const float* aw    = (const float*)d_in[15];
    const float* ab    = (const float*)d_in[16];
    const float* fcgw  = (const float*)d_in[17];
    const float* fcgb  = (const float*)d_in[18];
    const float* fccgw = (const float*)d_in[19];
    const float* fccgb = (const float*)d_in[20];

    // workspace layout: ~24.5M floats = 98 MB
    float* ws      = (float*)d_ws;
    float* dis     = ws;                          // 102400 fl
    int*   cnt     = (int*)(ws + 102400);         // 102400
    int*   starts  = cnt + 102400;                // 102400
    int*   cursor  = starts + 102400;             // 102400
    int*   bsum    = cursor + 102400;             // 512
    int*   boff    = bsum + 512;                  // 512
    int*   srclist = boff + 512;                  // 1,600,000
    float* h1      = (float*)(srclist + 1600000); // 12.8M  (reused as h2)
    float* c1      = h1 + 12800000;               // 6.4M   (reused: c2 @ +0, w2 @ +3.2M)
    float* w1      = c1 + 6400000;                // 3.2M
    float* c2      = c1;
    float* w2      = c1 + 3200000;

    float* z_a  = (float*)d_out;
    float* z_c  = z_a + (size_t)N_GRAPHS * 64;
    float* hout = z_a + (size_t)2 * N_GRAPHS * 64;

    // CSR build (shared by both layers)
    zero_cnt_k<<<(N_NODES + 255) / 256, 256, 0, stream>>>(cnt);
    count_k<<<(N_EDGES / 4 + 255) / 256, 256, 0, stream>>>(ei, cnt);
    scan_bsum_k<<<NB_SCAN, 256, 0, stream>>>(cnt, bsum);
    scan_boff_k<<<1, 512, 0, stream>>>(bsum, boff);
    scan_apply_k<<<NB_SCAN, 256, 0, stream>>>(cnt, boff, starts, cursor, dis);
    fill_k<<<(N_EDGES / 4 + 255) / 256, 256, 0, stream>>>(ei, cursor, srclist);

    // h1 = elu(x @ nfc_w^T + nfc_b)                       [100k,64]x[64,128]
    gemm_k<64, 128, 64, 4, 8, true, false, true>
        <<<(N_NODES + 63) / 64, 256, 0, stream>>>(x, nfc_w, nfc_b, dis, h1, N_NODES);
    // c1 = dis * (h1 @ g1bw^T)                            [100k,128]x[128,64]
    gemm_k<128, 64, 32, 2, 4, false, true, false>
        <<<(N_NODES + 31) / 32, 256, 0, stream>>>(h1, g1bw, nullptr, dis, c1, N_NODES);
    // w1 = h1 @ g1cw^T + g1cb                             [100k,128]x[128,32]
    gemm_k<128, 32, 64, 4, 2, false, false, true>
        <<<(N_NODES + 63) / 64, 256, 0, stream>>>(h1, g1cw, g1cb, dis, w1, N_NODES);
    // h2 = elu(dis * combine(w1, gather(c1)) + g1_bias)  -> h1 buffer
    gather1_k<<<N_NODES / 16, 256, 0, stream>>>(starts, cnt, srclist, c1, w1, dis, g1b, h1);
    // c2 = dis * (h2 @ g2bw^T)                            [100k,128]x[128,32]
    gemm_k<128, 32, 64, 4, 2, false, true, false>
        <<<(N_NODES + 63) / 64, 256, 0, stream>>>(h1, g2bw, nullptr, dis, c2, N_NODES);
    // w2 = h2 @ g2cw^T + g2cb
    gemm_k<128, 32, 64, 4, 2, false, false, true>
        <<<(N_NODES + 63) / 64, 256, 0, stream>>>(h1, g2cw, g2cb, dis, w2, N_NODES);
    // h = normalize(elu(dis * combine(w2, gather(c2)) + g2_bias))
    gather2_k<<<N_NODES / 8, 256, 0, stream>>>(starts, cnt, srclist, c2, w2, dis, g2b, hout);
    // per-graph pooling + attention heads
    graph_k<<<N_GRAPHS, 128, 0, stream>>>(hout, z_e, aw, ab, fcgw, fcgb, fccgw, fccgb, z_a, z_c);
}

// Round 6
// 508.628 us; speedup vs baseline: 1.3181x; 1.3181x over previous
//
#include <hip/hip_runtime.h>
#include <math.h>

#define N_NODES  100000
#define N_EDGES  1600000
#define N_GRAPHS 1000
#define NPG      100
#define NBKT     391          // ceil(100000/256); bucket = dst >> 8
#define EPB      4096         // edges per block in binning kernels

__device__ __forceinline__ float elu_f(float x) {
    return x > 0.0f ? x : expm1f(x);
}

// ---------------- binned CSR build ----------------
__global__ __launch_bounds__(512) void zero_bkt_k(int* __restrict__ bkt_cnt) {
    int t = threadIdx.x;
    if (t < NBKT) bkt_cnt[t] = 0;
}

// LDS histogram by bucket; one global atomic per bucket per block
__global__ __launch_bounds__(256) void bincount_k(const int* __restrict__ ei, int* __restrict__ bkt_cnt) {
    __shared__ int h[NBKT];
    const int t = threadIdx.x;
    for (int i = t; i < NBKT; i += 256) h[i] = 0;
    __syncthreads();
    const int4* dst4 = (const int4*)(ei + N_EDGES);
    int i0 = blockIdx.x * (EPB / 4);
    for (int i = t; i < EPB / 4; i += 256) {
        int g = i0 + i;
        if (g < N_EDGES / 4) {
            int4 d = dst4[g];
            atomicAdd(&h[d.x >> 8], 1);
            atomicAdd(&h[d.y >> 8], 1);
            atomicAdd(&h[d.z >> 8], 1);
            atomicAdd(&h[d.w >> 8], 1);
        }
    }
    __syncthreads();
    for (int i = t; i < NBKT; i += 256)
        if (h[i]) atomicAdd(&bkt_cnt[i], h[i]);
}

// single-block scan: bkt_start[0..NBKT] (exclusive, +total), init bkt_cursor
__global__ __launch_bounds__(512) void bkt_scan_k(const int* __restrict__ bkt_cnt,
                                                  int* __restrict__ bkt_start,
                                                  int* __restrict__ bkt_cursor)
{
    __shared__ int s[512];
    int t = threadIdx.x;
    s[t] = (t < NBKT) ? bkt_cnt[t] : 0;
    __syncthreads();
    #pragma unroll
    for (int off = 1; off < 512; off <<= 1) {
        int u = (t >= off) ? s[t - off] : 0;
        __syncthreads();
        s[t] += u;
        __syncthreads();
    }
    if (t <= NBKT) {
        int v = (t == 0) ? 0 : s[t - 1];
        bkt_start[t] = v;
        if (t < NBKT) bkt_cursor[t] = v;
    }
}

// scatter (src,dst) pairs into bucket-contiguous regions; block reserves ranges
__global__ __launch_bounds__(256) void binscatter_k(const int* __restrict__ ei,
                                                    int* __restrict__ bkt_cursor,
                                                    int2* __restrict__ pairs)
{
    __shared__ int h[NBKT];
    __shared__ int base[NBKT];
    const int t = threadIdx.x;
    for (int i = t; i < NBKT; i += 256) h[i] = 0;
    __syncthreads();
    const int4* src4 = (const int4*)ei;
    const int4* dst4 = (const int4*)(ei + N_EDGES);
    int i0 = blockIdx.x * (EPB / 4);
    for (int i = t; i < EPB / 4; i += 256) {
        int g = i0 + i;
        if (g < N_EDGES / 4) {
            int4 d = dst4[g];
            atomicAdd(&h[d.x >> 8], 1);
            atomicAdd(&h[d.y >> 8], 1);
            atomicAdd(&h[d.z >> 8], 1);
            atomicAdd(&h[d.w >> 8], 1);
        }
    }
    __syncthreads();
    for (int i = t; i < NBKT; i += 256) {
        int c = h[i];
        base[i] = c ? atomicAdd(&bkt_cursor[i], c) : 0;
        h[i] = 0;                       // reuse as local cursor
    }
    __syncthreads();
    for (int i = t; i < EPB / 4; i += 256) {
        int g = i0 + i;
        if (g < N_EDGES / 4) {
            int4 s4 = src4[g];
            int4 d4 = dst4[g];
            int b, r;
            b = d4.x >> 8; r = atomicAdd(&h[b], 1); pairs[base[b] + r] = make_int2(s4.x, d4.x);
            b = d4.y >> 8; r = atomicAdd(&h[b], 1); pairs[base[b] + r] = make_int2(s4.y, d4.y);
            b = d4.z >> 8; r = atomicAdd(&h[b], 1); pairs[base[b] + r] = make_int2(s4.z, d4.z);
            b = d4.w >> 8; r = atomicAdd(&h[b], 1); pairs[base[b] + r] = make_int2(s4.w, d4.w);
        }
    }
}

// one block per bucket: per-node CSR via LDS atomics; srclist writes stay in a 16KB window
__global__ __launch_bounds__(256) void bucket_csr_k(const int2* __restrict__ pairs,
                                                    const int* __restrict__ bkt_start,
                                                    int* __restrict__ starts,
                                                    int* __restrict__ cnt,
                                                    float* __restrict__ dis,
                                                    int* __restrict__ srclist)
{
    __shared__ int s[256];
    __shared__ int cur[256];
    const int b = blockIdx.x, t = threadIdx.x;
    const int lo = bkt_start[b], hi = bkt_start[b + 1];
    const int n0 = b << 8;
    const int nn = min(256, N_NODES - n0);

    s[t] = 0;
    __syncthreads();
    for (int i = lo + t; i < hi; i += 256) {
        int2 p = pairs[i];
        atomicAdd(&s[p.y & 255], 1);
    }
    __syncthreads();
    int v = s[t];
    __syncthreads();
    s[t] = v;
    __syncthreads();
    #pragma unroll
    for (int off = 1; off < 256; off <<= 1) {
        int u = (t >= off) ? s[t - off] : 0;
        __syncthreads();
        s[t] += u;
        __syncthreads();
    }
    int ex = lo + s[t] - v;            // global exclusive start for node n0+t
    if (t < nn) {
        starts[n0 + t] = ex;
        cnt[n0 + t] = v;
        dis[n0 + t] = rsqrtf(1.0f + (float)v);
    }
    cur[t] = ex;
    __syncthreads();
    for (int i = lo + t; i < hi; i += 256) {
        int2 p = pairs[i];
        int pos = atomicAdd(&cur[p.y & 255], 1);
        srclist[pos] = p.x;
    }
}

// ---------------- generic node GEMM: C = post(A[M,K] @ W[N,K]^T) ----------------
template<int K, int N, int NT, int TN, int TC, bool ELU, bool SCALE, bool BIAS>
__global__ __launch_bounds__(256) void gemm_k(
    const float* __restrict__ A, const float* __restrict__ W,
    const float* __restrict__ bias, const float* __restrict__ dis,
    float* __restrict__ C, int M)
{
    constexpr int CG = N / TC;
    static_assert((NT / TN) * CG == 256, "thread mapping");
    constexpr int KP = K + 4;
    constexpr int NP = N + 4;

    __shared__ float Xs[NT * KP];
    __shared__ float Ws[K * NP];

    const int t = threadIdx.x;
    const int node0 = blockIdx.x * NT;

    for (int idx = t; idx < N * K; idx += 256) {
        int j = idx / K, k = idx % K;
        Ws[k * NP + j] = W[idx];
    }
    for (int idx = t; idx < NT * K; idx += 256) {
        int n = idx / K, k = idx % K;
        int gn = node0 + n;
        Xs[n * KP + k] = (gn < M) ? A[(size_t)gn * K + k] : 0.0f;
    }
    __syncthreads();

    const int ng = t / CG;
    const int cg = t % CG;

    float acc[TN][TC];
    #pragma unroll
    for (int i = 0; i < TN; ++i)
        #pragma unroll
        for (int j = 0; j < TC; ++j) acc[i][j] = 0.0f;

    #pragma unroll 4
    for (int k = 0; k < K; ++k) {
        float xv[TN];
        #pragma unroll
        for (int i = 0; i < TN; ++i) xv[i] = Xs[(ng * TN + i) * KP + k];
        const float* wr = &Ws[k * NP + cg * TC];
        float wv[TC];
        if constexpr (TC % 4 == 0) {
            #pragma unroll
            for (int j4 = 0; j4 < TC / 4; ++j4) {
                float4 v = *(const float4*)(wr + 4 * j4);
                wv[4*j4+0] = v.x; wv[4*j4+1] = v.y; wv[4*j4+2] = v.z; wv[4*j4+3] = v.w;
            }
        } else {
            float2 v = *(const float2*)wr;
            wv[0] = v.x; wv[1] = v.y;
        }
        #pragma unroll
        for (int j = 0; j < TC; ++j)
            #pragma unroll
            for (int i = 0; i < TN; ++i)
                acc[i][j] = fmaf(xv[i], wv[j], acc[i][j]);
    }

    #pragma unroll
    for (int i = 0; i < TN; ++i) {
        int gn = node0 + ng * TN + i;
        if (gn >= M) continue;
        float scale = 1.0f;
        if constexpr (SCALE) scale = dis[gn];
        #pragma unroll
        for (int j = 0; j < TC; ++j) {
            float v = acc[i][j];
            if constexpr (BIAS) v += bias[cg * TC + j];
            if constexpr (ELU)  v = elu_f(v);
            if constexpr (SCALE) v *= scale;
            C[(size_t)gn * N + cg * TC + j] = v;
        }
    }
}

// ---------------- layer-1 gather + combine + elu (divergence-safe, no shfl) ----------------
// block = 256 = 16 nodes x 16 threads; thread owns 4 features (float4) of c (64 feats)
__global__ __launch_bounds__(256) void gather1_k(
    const int* __restrict__ starts, const int* __restrict__ cnt,
    const int* __restrict__ srclist, const float* __restrict__ c,
    const float* __restrict__ w1, const float* __restrict__ dis,
    const float* __restrict__ bias, float* __restrict__ h2)
{
    __shared__ float aggS[16][68];
    __shared__ float w1S[16][32];

    const int t = threadIdx.x;
    const int nn = t >> 4;            // node within block
    const int q  = t & 15;            // feature quad
    const int n  = blockIdx.x * 16 + nn;

    // stage w1 tile (coalesced): 16 nodes x 32 floats = 512
    {
        int i0 = t * 2;
        int wn = i0 >> 5, wj = i0 & 31;
        float2 v = *(const float2*)(w1 + (size_t)(blockIdx.x * 16 + wn) * 32 + wj);
        w1S[wn][wj] = v.x;
        w1S[wn][wj + 1] = v.y;
    }

    const int s0 = starts[n];
    const int cn = cnt[n];
    float4 a = *(const float4*)(c + (size_t)n * 64 + q * 4);   // self term
    for (int j = 0; j < cn; ++j) {
        int src = srclist[s0 + j];                              // broadcast within group
        float4 v = *(const float4*)(c + (size_t)src * 64 + q * 4);
        a.x += v.x; a.y += v.y; a.z += v.z; a.w += v.w;
    }
    aggS[nn][q * 4 + 0] = a.x;
    aggS[nn][q * 4 + 1] = a.y;
    aggS[nn][q * 4 + 2] = a.z;
    aggS[nn][q * 4 + 3] = a.w;
    __syncthreads();

    // combine: thread (nn,q) computes outputs j = r*16 + q for r = 0..7 (f = q)
    float ab[4];
    #pragma unroll
    for (int b = 0; b < 4; ++b) ab[b] = aggS[nn][b * 16 + q];
    const float dn = dis[n];
    float* out = h2 + (size_t)n * 128;
    #pragma unroll
    for (int r = 0; r < 8; ++r) {
        float s = 0.0f;
        #pragma unroll
        for (int b = 0; b < 4; ++b) s = fmaf(w1S[nn][r * 4 + b], ab[b], s);
        out[r * 16 + q] = elu_f(s * dn + bias[r * 16 + q]);
    }
}

// ---------------- layer-2 gather + combine + elu + L2 normalize (divergence-safe) ----------------
// block = 256 = 8 nodes x 32 threads; thread owns 1 feature of c (32 feats)
__global__ __launch_bounds__(256) void gather2_k(
    const int* __restrict__ starts, const int* __restrict__ cnt,
    const int* __restrict__ srclist, const float* __restrict__ c,
    const float* __restrict__ w2, const float* __restrict__ dis,
    const float* __restrict__ bias, float* __restrict__ hout)
{
    __shared__ float aggS[8][36];
    __shared__ float w2S[8][32];

    const int t = threadIdx.x;
    const int nn = t >> 5;            // node within block
    const int q  = t & 31;            // feature
    const int n  = blockIdx.x * 8 + nn;

    // stage w2 tile (coalesced): 8 nodes x 32 floats = 256
    w2S[t >> 5][t & 31] = w2[(size_t)(blockIdx.x * 8 + (t >> 5)) * 32 + (t & 31)];

    const int s0 = starts[n];
    const int cn = cnt[n];
    float a = c[(size_t)n * 32 + q];                            // self term
    for (int j = 0; j < cn; ++j) {
        int src = srclist[s0 + j];
        a += c[(size_t)src * 32 + q];
    }
    aggS[nn][q] = a;
    __syncthreads();

    // combine: thread (nn,q) computes outputs j1 = q, j2 = q + 32
    const int f  = q & 7;
    const int hh = q >> 3;
    float ab[4];
    #pragma unroll
    for (int b = 0; b < 4; ++b) ab[b] = aggS[nn][b * 8 + f];
    const float dn = dis[n];
    float s1 = 0.0f, s2 = 0.0f;
    #pragma unroll
    for (int b = 0; b < 4; ++b) {
        s1 = fmaf(w2S[nn][hh * 4 + b], ab[b], s1);
        s2 = fmaf(w2S[nn][(hh + 4) * 4 + b], ab[b], s2);
    }
    s1 = elu_f(s1 * dn + bias[q]);
    s2 = elu_f(s2 * dn + bias[q + 32]);

    // L2 norm across the node's 64 outputs: reduce s1^2+s2^2 over the aligned 32-thread group
    float tot = s1 * s1 + s2 * s2;
    #pragma unroll
    for (int o = 1; o < 32; o <<= 1) tot += __shfl_xor(tot, o, 64);
    float inv = 1.0f / fmaxf(sqrtf(tot), 1e-12f);
    hout[(size_t)n * 64 + q]      = s1 * inv;
    hout[(size_t)n * 64 + 32 + q] = s2 * inv;
}

// ---------------- per-graph tail: z_a, attention softmax, z_c ----------------
__global__ __launch_bounds__(128) void graph_k(const float* __restrict__ h,
                                               const float* __restrict__ z_e,
                                               const float* __restrict__ aw,
                                               const float* __restrict__ ab,
                                               const float* __restrict__ fcgw,
                                               const float* __restrict__ fcgb,
                                               const float* __restrict__ fccgw,
                                               const float* __restrict__ fccgb,
                                               float* __restrict__ z_a,
                                               float* __restrict__ z_c)
{
    __shared__ float Hs[NPG * 64];
    __shared__ float sumh[64], wsh[64], lg[NPG], ex[NPG];
    __shared__ float red[2];
    int g = blockIdx.x, t = threadIdx.x;
    const float* hg = h + (size_t)g * NPG * 64;
    for (int idx = t; idx < NPG * 64; idx += 128) Hs[idx] = hg[idx];
    __syncthreads();

    if (t < 64) {
        float s = 0.0f;
        for (int n = 0; n < NPG; ++n) s += Hs[n * 64 + t];
        sumh[t] = s;
    }
    __syncthreads();

    if (t < 64) {
        float acc = fcgb[t];
        for (int f = 0; f < 64; ++f) acc = fmaf(sumh[f], fcgw[t * 64 + f], acc);
        z_a[(size_t)g * 64 + t] = acc;
    }
    if (t < NPG) {
        float zd = 0.0f;
        for (int q = 0; q < 32; ++q) zd = fmaf(z_e[(size_t)g * 32 + q], aw[64 + q], zd);
        float dot = 0.0f;
        for (int k0 = 0; k0 < 64; ++k0) {
            int k = (k0 + t) & 63;
            dot = fmaf(Hs[t * 64 + k], aw[k], dot);
        }
        lg[t] = dot + zd + ab[0] + 1e-16f;
    }
    __syncthreads();

    if (t < 64) {
        float m = -INFINITY;
        for (int n = t; n < NPG; n += 64) m = fmaxf(m, lg[n]);
        #pragma unroll
        for (int o = 1; o < 64; o <<= 1) m = fmaxf(m, __shfl_xor(m, o, 64));
        if (t == 0) red[0] = m;
    }
    __syncthreads();
    float m = red[0];
    if (t < NPG) ex[t] = expf(lg[t] - m);
    __syncthreads();
    if (t < 64) {
        float s = 0.0f;
        for (int n = t; n < NPG; n += 64) s += ex[n];
        #pragma unroll
        for (int o = 1; o < 64; o <<= 1) s += __shfl_xor(s, o, 64);
        if (t == 0) red[1] = s + 1e-16f;
    }
    __syncthreads();
    float inv_denom = 1.0f / red[1];
    if (t < 64) {
        float a = 0.0f;
        for (int n = 0; n < NPG; ++n) a = fmaf(ex[n], Hs[n * 64 + t], a);
        wsh[t] = a * inv_denom;
    }
    __syncthreads();
    if (t < 64) {
        float acc = fccgb[t];
        for (int f = 0; f < 64; ++f) acc = fmaf(wsh[f], fccgw[t * 64 + f], acc);
        z_c[(size_t)g * 64 + t] = acc;
    }
}

extern "C" void kernel_launch(void* const* d_in, const int* in_sizes, int n_in,
                              void* d_out, int out_size, void* d_ws, size_t ws_size,
                              hipStream_t stream)
{
    const float* x     = (const float*)d_in[0];
    const int*   ei    = (const int*)d_in[1];
    const float* z_e   = (const float*)d_in[4];
    const float* nfc_w = (const float*)d_in[5];
    const float* nfc_b = (const float*)d_in[6];
    const float* g1bw  = (const float*)d_in[7];
    const float* g1cw  = (const float*)d_in[8];
    const float* g1cb  = (const float*)d_in[9];
    const float* g1b   = (const float*)d_in[10];
    const float* g2bw  = (const float*)d_in[11];
    const float* g2cw  = (const float*)d_in[12];
    const float* g2cb  = (const float*)d_in[13];
    const float* g2b   = (const float*)d_in[14];
    const float* aw    = (const float*)d_in[15];
    const float* ab    = (const float*)d_in[16];
    const float* fcgw  = (const float*)d_in[17];
    const float* fcgb  = (const float*)d_in[18];
    const float* fccgw = (const float*)d_in[19];
    const float* fccgb = (const float*)d_in[20];

    // workspace layout (~97 MB)
    float* ws        = (float*)d_ws;
    float* dis       = ws;                           // 102400 fl
    int*   cnt       = (int*)(ws + 102400);          // 102400
    int*   starts    = cnt + 102400;                 // 102400
    int*   bkt_cnt   = starts + 102400;              // 512
    int*   bkt_start = bkt_cnt + 512;                // 512
    int*   bkt_cur   = bkt_start + 512;              // 512
    int*   srclist   = bkt_cur + 512;                // 1,600,000
    float* h1        = (float*)(srclist + 1600000);  // 12.8M fl (reused as h2)
    float* c1        = h1 + 12800000;                // 6.4M  (reused: c2 @ +0, w2 @ +3.2M)
    float* w1        = c1 + 6400000;                 // 3.2M
    float* c2        = c1;
    float* w2        = c1 + 3200000;
    int2*  pairs     = (int2*)h1;                    // 1.6M int2 = 12.8MB, dead before h1 written

    float* z_a  = (float*)d_out;
    float* z_c  = z_a + (size_t)N_GRAPHS * 64;
    float* hout = z_a + (size_t)2 * N_GRAPHS * 64;

    // binned CSR build (all fine-grained atomics in LDS; global writes line-local)
    zero_bkt_k<<<1, 512, 0, stream>>>(bkt_cnt);
    bincount_k<<<(N_EDGES + EPB - 1) / EPB, 256, 0, stream>>>(ei, bkt_cnt);
    bkt_scan_k<<<1, 512, 0, stream>>>(bkt_cnt, bkt_start, bkt_cur);
    binscatter_k<<<(N_EDGES + EPB - 1) / EPB, 256, 0, stream>>>(ei, bkt_cur, pairs);
    bucket_csr_k<<<NBKT, 256, 0, stream>>>(pairs, bkt_start, starts, cnt, dis, srclist);

    // h1 = elu(x @ nfc_w^T + nfc_b)                       [100k,64]x[64,128]
    gemm_k<64, 128, 64, 4, 8, true, false, true>
        <<<(N_NODES + 63) / 64, 256, 0, stream>>>(x, nfc_w, nfc_b, dis, h1, N_NODES);
    // c1 = dis * (h1 @ g1bw^T)                            [100k,128]x[128,64]
    gemm_k<128, 64, 32, 2, 4, false, true, false>
        <<<(N_NODES + 31) / 32, 256, 0, stream>>>(h1, g1bw, nullptr, dis, c1, N_NODES);
    // w1 = h1 @ g1cw^T + g1cb                             [100k,128]x[128,32]
    gemm_k<128, 32, 64, 4, 2, false, false, true>
        <<<(N_NODES + 63) / 64, 256, 0, stream>>>(h1, g1cw, g1cb, dis, w1, N_NODES);
    // h2 = elu(dis * combine(w1, gather(c1)) + g1_bias)  -> h1 buffer
    gather1_k<<<N_NODES / 16, 256, 0, stream>>>(starts, cnt, srclist, c1, w1, dis, g1b, h1);
    // c2 = dis * (h2 @ g2bw^T)                            [100k,128]x[128,32]
    gemm_k<128, 32, 64, 4, 2, false, true, false>
        <<<(N_NODES + 63) / 64, 256, 0, stream>>>(h1, g2bw, nullptr, dis, c2, N_NODES);
    // w2 = h2 @ g2cw^T + g2cb
    gemm_k<128, 32, 64, 4, 2, false, false, true>
        <<<(N_NODES + 63) / 64, 256, 0, stream>>>(h1, g2cw, g2cb, dis, w2, N_NODES);
    // h = normalize(elu(dis * combine(w2, gather(c2)) + g2_bias))
    gather2_k<<<N_NODES / 8, 256, 0, stream>>>(starts, cnt, srclist, c2, w2, dis, g2b, hout);
    // per-graph pooling + attention heads
    graph_k<<<N_GRAPHS, 128, 0, stream>>>(hout, z_e, aw, ab, fcgw, fcgb, fccgw, fccgb, z_a, z_c);
}

// Round 7
// 458.937 us; speedup vs baseline: 1.4608x; 1.1083x over previous
//
#include <hip/hip_runtime.h>
#include <hip/hip_bf16.h>
#include <math.h>

#define N_NODES  100000
#define N_EDGES  1600000
#define N_GRAPHS 1000
#define NPG      100
#define NBKT     391          // ceil(100000/256); bucket = dst >> 8
#define EPB      4096         // edges per block in binning kernels

__device__ __forceinline__ float elu_f(float x) {
    return x > 0.0f ? x : expm1f(x);
}

__device__ __forceinline__ float bf2f(unsigned int u16) {   // low 16 bits hold bf16
    union { unsigned int i; float f; } v; v.i = u16 << 16; return v.f;
}
__device__ __forceinline__ unsigned short f2bf(float f) {
    __hip_bfloat16 h = __float2bfloat16(f);
    return *reinterpret_cast<unsigned short*>(&h);
}

// ---------------- binned CSR build ----------------
__global__ __launch_bounds__(512) void zero_bkt_k(int* __restrict__ bkt_cnt) {
    int t = threadIdx.x;
    if (t < NBKT) bkt_cnt[t] = 0;
}

__global__ __launch_bounds__(256) void bincount_k(const int* __restrict__ ei, int* __restrict__ bkt_cnt) {
    __shared__ int h[NBKT];
    const int t = threadIdx.x;
    for (int i = t; i < NBKT; i += 256) h[i] = 0;
    __syncthreads();
    const int4* dst4 = (const int4*)(ei + N_EDGES);
    int i0 = blockIdx.x * (EPB / 4);
    for (int i = t; i < EPB / 4; i += 256) {
        int g = i0 + i;
        if (g < N_EDGES / 4) {
            int4 d = dst4[g];
            atomicAdd(&h[d.x >> 8], 1);
            atomicAdd(&h[d.y >> 8], 1);
            atomicAdd(&h[d.z >> 8], 1);
            atomicAdd(&h[d.w >> 8], 1);
        }
    }
    __syncthreads();
    for (int i = t; i < NBKT; i += 256)
        if (h[i]) atomicAdd(&bkt_cnt[i], h[i]);
}

__global__ __launch_bounds__(512) void bkt_scan_k(const int* __restrict__ bkt_cnt,
                                                  int* __restrict__ bkt_start,
                                                  int* __restrict__ bkt_cursor)
{
    __shared__ int s[512];
    int t = threadIdx.x;
    s[t] = (t < NBKT) ? bkt_cnt[t] : 0;
    __syncthreads();
    #pragma unroll
    for (int off = 1; off < 512; off <<= 1) {
        int u = (t >= off) ? s[t - off] : 0;
        __syncthreads();
        s[t] += u;
        __syncthreads();
    }
    if (t <= NBKT) {
        int v = (t == 0) ? 0 : s[t - 1];
        bkt_start[t] = v;
        if (t < NBKT) bkt_cursor[t] = v;
    }
}

__global__ __launch_bounds__(256) void binscatter_k(const int* __restrict__ ei,
                                                    int* __restrict__ bkt_cursor,
                                                    int2* __restrict__ pairs)
{
    __shared__ int h[NBKT];
    __shared__ int base[NBKT];
    const int t = threadIdx.x;
    for (int i = t; i < NBKT; i += 256) h[i] = 0;
    __syncthreads();
    const int4* src4 = (const int4*)ei;
    const int4* dst4 = (const int4*)(ei + N_EDGES);
    int i0 = blockIdx.x * (EPB / 4);
    for (int i = t; i < EPB / 4; i += 256) {
        int g = i0 + i;
        if (g < N_EDGES / 4) {
            int4 d = dst4[g];
            atomicAdd(&h[d.x >> 8], 1);
            atomicAdd(&h[d.y >> 8], 1);
            atomicAdd(&h[d.z >> 8], 1);
            atomicAdd(&h[d.w >> 8], 1);
        }
    }
    __syncthreads();
    for (int i = t; i < NBKT; i += 256) {
        int c = h[i];
        base[i] = c ? atomicAdd(&bkt_cursor[i], c) : 0;
        h[i] = 0;
    }
    __syncthreads();
    for (int i = t; i < EPB / 4; i += 256) {
        int g = i0 + i;
        if (g < N_EDGES / 4) {
            int4 s4 = src4[g];
            int4 d4 = dst4[g];
            int b, r;
            b = d4.x >> 8; r = atomicAdd(&h[b], 1); pairs[base[b] + r] = make_int2(s4.x, d4.x);
            b = d4.y >> 8; r = atomicAdd(&h[b], 1); pairs[base[b] + r] = make_int2(s4.y, d4.y);
            b = d4.z >> 8; r = atomicAdd(&h[b], 1); pairs[base[b] + r] = make_int2(s4.z, d4.z);
            b = d4.w >> 8; r = atomicAdd(&h[b], 1); pairs[base[b] + r] = make_int2(s4.w, d4.w);
        }
    }
}

__global__ __launch_bounds__(256) void bucket_csr_k(const int2* __restrict__ pairs,
                                                    const int* __restrict__ bkt_start,
                                                    int* __restrict__ starts,
                                                    int* __restrict__ cnt,
                                                    float* __restrict__ dis,
                                                    int* __restrict__ srclist)
{
    __shared__ int s[256];
    __shared__ int cur[256];
    const int b = blockIdx.x, t = threadIdx.x;
    const int lo = bkt_start[b], hi = bkt_start[b + 1];
    const int n0 = b << 8;
    const int nn = min(256, N_NODES - n0);

    s[t] = 0;
    __syncthreads();
    for (int i = lo + t; i < hi; i += 256) {
        int2 p = pairs[i];
        atomicAdd(&s[p.y & 255], 1);
    }
    __syncthreads();
    int v = s[t];
    __syncthreads();
    s[t] = v;
    __syncthreads();
    #pragma unroll
    for (int off = 1; off < 256; off <<= 1) {
        int u = (t >= off) ? s[t - off] : 0;
        __syncthreads();
        s[t] += u;
        __syncthreads();
    }
    int ex = lo + s[t] - v;
    if (t < nn) {
        starts[n0 + t] = ex;
        cnt[n0 + t] = v;
        dis[n0 + t] = rsqrtf(1.0f + (float)v);
    }
    cur[t] = ex;
    __syncthreads();
    for (int i = lo + t; i < hi; i += 256) {
        int2 p = pairs[i];
        int pos = atomicAdd(&cur[p.y & 255], 1);
        srclist[pos] = p.x;
    }
}

// ---------------- generic node GEMM: C = post(A[M,K] @ W[N,K]^T) ----------------
// BF16OUT: store C as bf16 (packed)
template<int K, int N, int NT, int TN, int TC, bool ELU, bool SCALE, bool BIAS, bool BF16OUT>
__global__ __launch_bounds__(256) void gemm_k(
    const float* __restrict__ A, const float* __restrict__ W,
    const float* __restrict__ bias, const float* __restrict__ dis,
    float* __restrict__ C, int M)
{
    constexpr int CG = N / TC;
    static_assert((NT / TN) * CG == 256, "thread mapping");
    constexpr int KP = K + 4;
    constexpr int NP = N + 4;

    __shared__ float Xs[NT * KP];
    __shared__ float Ws[K * NP];

    const int t = threadIdx.x;
    const int node0 = blockIdx.x * NT;

    for (int idx = t; idx < N * K; idx += 256) {
        int j = idx / K, k = idx % K;
        Ws[k * NP + j] = W[idx];
    }
    for (int idx = t; idx < NT * K; idx += 256) {
        int n = idx / K, k = idx % K;
        int gn = node0 + n;
        Xs[n * KP + k] = (gn < M) ? A[(size_t)gn * K + k] : 0.0f;
    }
    __syncthreads();

    const int ng = t / CG;
    const int cg = t % CG;

    float acc[TN][TC];
    #pragma unroll
    for (int i = 0; i < TN; ++i)
        #pragma unroll
        for (int j = 0; j < TC; ++j) acc[i][j] = 0.0f;

    #pragma unroll 4
    for (int k = 0; k < K; ++k) {
        float xv[TN];
        #pragma unroll
        for (int i = 0; i < TN; ++i) xv[i] = Xs[(ng * TN + i) * KP + k];
        const float* wr = &Ws[k * NP + cg * TC];
        float wv[TC];
        if constexpr (TC % 4 == 0) {
            #pragma unroll
            for (int j4 = 0; j4 < TC / 4; ++j4) {
                float4 v = *(const float4*)(wr + 4 * j4);
                wv[4*j4+0] = v.x; wv[4*j4+1] = v.y; wv[4*j4+2] = v.z; wv[4*j4+3] = v.w;
            }
        } else {
            float2 v = *(const float2*)wr;
            wv[0] = v.x; wv[1] = v.y;
        }
        #pragma unroll
        for (int j = 0; j < TC; ++j)
            #pragma unroll
            for (int i = 0; i < TN; ++i)
                acc[i][j] = fmaf(xv[i], wv[j], acc[i][j]);
    }

    #pragma unroll
    for (int i = 0; i < TN; ++i) {
        int gn = node0 + ng * TN + i;
        if (gn >= M) continue;
        float scale = 1.0f;
        if constexpr (SCALE) scale = dis[gn];
        size_t o0 = (size_t)gn * N + cg * TC;
        unsigned short tmp[TC];
        #pragma unroll
        for (int j = 0; j < TC; ++j) {
            float v = acc[i][j];
            if constexpr (BIAS) v += bias[cg * TC + j];
            if constexpr (ELU)  v = elu_f(v);
            if constexpr (SCALE) v *= scale;
            if constexpr (BF16OUT) tmp[j] = f2bf(v);
            else                   C[o0 + j] = v;
        }
        if constexpr (BF16OUT) {
            unsigned short* cb = (unsigned short*)C;
            if constexpr (TC == 4)      *(ushort4*)(cb + o0) = *(ushort4*)tmp;
            else if constexpr (TC == 2) *(ushort2*)(cb + o0) = *(ushort2*)tmp;
            else {
                #pragma unroll
                for (int j = 0; j < TC; ++j) cb[o0 + j] = tmp[j];
            }
        }
    }
}

// ---------------- layer-1 gather + combine + elu (c in bf16) ----------------
// block = 256 = 16 nodes x 16 threads; thread owns 4 feats = 8B of c (64 feats)
__global__ __launch_bounds__(256) void gather1_k(
    const int* __restrict__ starts, const int* __restrict__ cnt,
    const int* __restrict__ srclist, const unsigned short* __restrict__ c,
    const float* __restrict__ w1, const float* __restrict__ dis,
    const float* __restrict__ bias, float* __restrict__ h2)
{
    __shared__ float aggS[16][68];
    __shared__ float w1S[16][32];

    const int t = threadIdx.x;
    const int nn = t >> 4;
    const int q  = t & 15;
    const int n  = blockIdx.x * 16 + nn;

    {
        int i0 = t * 2;
        int wn = i0 >> 5, wj = i0 & 31;
        float2 v = *(const float2*)(w1 + (size_t)(blockIdx.x * 16 + wn) * 32 + wj);
        w1S[wn][wj] = v.x;
        w1S[wn][wj + 1] = v.y;
    }

    const int s0 = starts[n];
    const int cn = cnt[n];
    float a0, a1, a2, a3;
    {
        uint2 u = *(const uint2*)(c + (size_t)n * 64 + q * 4);
        a0 = bf2f(u.x & 0xffff); a1 = bf2f(u.x >> 16);
        a2 = bf2f(u.y & 0xffff); a3 = bf2f(u.y >> 16);
    }
    for (int j = 0; j < cn; ++j) {
        int src = srclist[s0 + j];
        uint2 u = *(const uint2*)(c + (size_t)src * 64 + q * 4);
        a0 += bf2f(u.x & 0xffff); a1 += bf2f(u.x >> 16);
        a2 += bf2f(u.y & 0xffff); a3 += bf2f(u.y >> 16);
    }
    aggS[nn][q * 4 + 0] = a0;
    aggS[nn][q * 4 + 1] = a1;
    aggS[nn][q * 4 + 2] = a2;
    aggS[nn][q * 4 + 3] = a3;
    __syncthreads();

    float ab[4];
    #pragma unroll
    for (int b = 0; b < 4; ++b) ab[b] = aggS[nn][b * 16 + q];
    const float dn = dis[n];
    float* out = h2 + (size_t)n * 128;
    #pragma unroll
    for (int r = 0; r < 8; ++r) {
        float s = 0.0f;
        #pragma unroll
        for (int b = 0; b < 4; ++b) s = fmaf(w1S[nn][r * 4 + b], ab[b], s);
        out[r * 16 + q] = elu_f(s * dn + bias[r * 16 + q]);
    }
}

// ---------------- layer-2 gather + combine + elu + L2 normalize (c in bf16) ----------------
// block = 256 = 16 nodes x 16 threads; thread owns 2 feats = 4B of c (32 feats)
__global__ __launch_bounds__(256) void gather2_k(
    const int* __restrict__ starts, const int* __restrict__ cnt,
    const int* __restrict__ srclist, const unsigned short* __restrict__ c,
    const float* __restrict__ w2, const float* __restrict__ dis,
    const float* __restrict__ bias, float* __restrict__ hout)
{
    __shared__ float aggS[16][36];
    __shared__ float w2S[16][32];

    const int t = threadIdx.x;
    const int nn = t >> 4;
    const int q  = t & 15;
    const int n  = blockIdx.x * 16 + nn;

    {
        int i0 = t * 2;
        int wn = i0 >> 5, wj = i0 & 31;
        float2 v = *(const float2*)(w2 + (size_t)(blockIdx.x * 16 + wn) * 32 + wj);
        w2S[wn][wj] = v.x;
        w2S[wn][wj + 1] = v.y;
    }

    const int s0 = starts[n];
    const int cn = cnt[n];
    float a0, a1;
    {
        unsigned int u = *(const unsigned int*)(c + (size_t)n * 32 + q * 2);
        a0 = bf2f(u & 0xffff); a1 = bf2f(u >> 16);
    }
    for (int j = 0; j < cn; ++j) {
        int src = srclist[s0 + j];
        unsigned int u = *(const unsigned int*)(c + (size_t)src * 32 + q * 2);
        a0 += bf2f(u & 0xffff); a1 += bf2f(u >> 16);
    }
    aggS[nn][q * 2 + 0] = a0;
    aggS[nn][q * 2 + 1] = a1;
    __syncthreads();

    // combine: thread (nn,q) computes outputs j = r*16 + q for r = 0..3
    const float dn = dis[n];
    float sv[4];
    #pragma unroll
    for (int r = 0; r < 4; ++r) {
        int j = r * 16 + q;
        int hh = j >> 3, f = j & 7;
        float s = 0.0f;
        #pragma unroll
        for (int b = 0; b < 4; ++b) s = fmaf(w2S[nn][hh * 4 + b], aggS[nn][b * 8 + f], s);
        sv[r] = elu_f(s * dn + bias[j]);
    }

    // L2 norm across the node's 64 outputs (16 aligned lanes x 4 each)
    float tot = sv[0]*sv[0] + sv[1]*sv[1] + sv[2]*sv[2] + sv[3]*sv[3];
    #pragma unroll
    for (int o = 1; o < 16; o <<= 1) tot += __shfl_xor(tot, o, 64);
    float inv = 1.0f / fmaxf(sqrtf(tot), 1e-12f);
    float* out = hout + (size_t)n * 64;
    #pragma unroll
    for (int r = 0; r < 4; ++r) out[r * 16 + q] = sv[r] * inv;
}

// ---------------- per-graph tail: z_a, attention softmax, z_c ----------------
__global__ __launch_bounds__(128) void graph_k(const float* __restrict__ h,
                                               const float* __restrict__ z_e,
                                               const float* __restrict__ aw,
                                               const float* __restrict__ ab,
                                               const float* __restrict__ fcgw,
                                               const float* __restrict__ fcgb,
                                               const float* __restrict__ fccgw,
                                               const float* __restrict__ fccgb,
                                               float* __restrict__ z_a,
                                               float* __restrict__ z_c)
{
    __shared__ float Hs[NPG * 64];
    __shared__ float sumh[64], wsh[64], lg[NPG], ex[NPG];
    __shared__ float red[2];
    int g = blockIdx.x, t = threadIdx.x;
    const float* hg = h + (size_t)g * NPG * 64;
    for (int idx = t; idx < NPG * 64; idx += 128) Hs[idx] = hg[idx];
    __syncthreads();

    if (t < 64) {
        float s = 0.0f;
        for (int n = 0; n < NPG; ++n) s += Hs[n * 64 + t];
        sumh[t] = s;
    }
    __syncthreads();

    if (t < 64) {
        float acc = fcgb[t];
        for (int f = 0; f < 64; ++f) acc = fmaf(sumh[f], fcgw[t * 64 + f], acc);
        z_a[(size_t)g * 64 + t] = acc;
    }
    if (t < NPG) {
        float zd = 0.0f;
        for (int q = 0; q < 32; ++q) zd = fmaf(z_e[(size_t)g * 32 + q], aw[64 + q], zd);
        float dot = 0.0f;
        for (int k0 = 0; k0 < 64; ++k0) {
            int k = (k0 + t) & 63;
            dot = fmaf(Hs[t * 64 + k], aw[k], dot);
        }
        lg[t] = dot + zd + ab[0] + 1e-16f;
    }
    __syncthreads();

    if (t < 64) {
        float m = -INFINITY;
        for (int n = t; n < NPG; n += 64) m = fmaxf(m, lg[n]);
        #pragma unroll
        for (int o = 1; o < 64; o <<= 1) m = fmaxf(m, __shfl_xor(m, o, 64));
        if (t == 0) red[0] = m;
    }
    __syncthreads();
    float m = red[0];
    if (t < NPG) ex[t] = expf(lg[t] - m);
    __syncthreads();
    if (t < 64) {
        float s = 0.0f;
        for (int n = t; n < NPG; n += 64) s += ex[n];
        #pragma unroll
        for (int o = 1; o < 64; o <<= 1) s += __shfl_xor(s, o, 64);
        if (t == 0) red[1] = s + 1e-16f;
    }
    __syncthreads();
    float inv_denom = 1.0f / red[1];
    if (t < 64) {
        float a = 0.0f;
        for (int n = 0; n < NPG; ++n) a = fmaf(ex[n], Hs[n * 64 + t], a);
        wsh[t] = a * inv_denom;
    }
    __syncthreads();
    if (t < 64) {
        float acc = fccgb[t];
        for (int f = 0; f < 64; ++f) acc = fmaf(wsh[f], fccgw[t * 64 + f], acc);
        z_c[(size_t)g * 64 + t] = acc;
    }
}

extern "C" void kernel_launch(void* const* d_in, const int* in_sizes, int n_in,
                              void* d_out, int out_size, void* d_ws, size_t ws_size,
                              hipStream_t stream)
{
    const float* x     = (const float*)d_in[0];
    const int*   ei    = (const int*)d_in[1];
    const float* z_e   = (const float*)d_in[4];
    const float* nfc_w = (const float*)d_in[5];
    const float* nfc_b = (const float*)d_in[6];
    const float* g1bw  = (const float*)d_in[7];
    const float* g1cw  = (const float*)d_in[8];
    const float* g1cb  = (const float*)d_in[9];
    const float* g1b   = (const float*)d_in[10];
    const float* g2bw  = (const float*)d_in[11];
    const float* g2cw  = (const float*)d_in[12];
    const float* g2cb  = (const float*)d_in[13];
    const float* g2b   = (const float*)d_in[14];
    const float* aw    = (const float*)d_in[15];
    const float* ab    = (const float*)d_in[16];
    const float* fcgw  = (const float*)d_in[17];
    const float* fcgb  = (const float*)d_in[18];
    const float* fccgw = (const float*)d_in[19];
    const float* fccgb = (const float*)d_in[20];

    // workspace layout (~90 MB)
    float* ws        = (float*)d_ws;
    float* dis       = ws;                           // 102400 fl
    int*   cnt       = (int*)(ws + 102400);          // 102400
    int*   starts    = cnt + 102400;                 // 102400
    int*   bkt_cnt   = starts + 102400;              // 512
    int*   bkt_start = bkt_cnt + 512;                // 512
    int*   bkt_cur   = bkt_start + 512;              // 512
    int*   srclist   = bkt_cur + 512;                // 1,600,000
    float* h1        = (float*)(srclist + 1600000);  // 12.8M fl (reused as h2)
    float* c1f       = h1 + 12800000;                // region: c1 bf16 (3.2M fl), c2 bf16 aliased
    float* w1        = c1f + 3200000;                // 3.2M fl
    float* w2        = w1 + 3200000;                 // 3.2M fl
    unsigned short* c1 = (unsigned short*)c1f;       // 6.4M bf16 = 12.8 MB
    unsigned short* c2 = (unsigned short*)c1f;       // 3.2M bf16 (c1 dead by then)
    int2*  pairs     = (int2*)h1;                    // 12.8MB, dead before h1 written

    float* z_a  = (float*)d_out;
    float* z_c  = z_a + (size_t)N_GRAPHS * 64;
    float* hout = z_a + (size_t)2 * N_GRAPHS * 64;

    // binned CSR build
    zero_bkt_k<<<1, 512, 0, stream>>>(bkt_cnt);
    bincount_k<<<(N_EDGES + EPB - 1) / EPB, 256, 0, stream>>>(ei, bkt_cnt);
    bkt_scan_k<<<1, 512, 0, stream>>>(bkt_cnt, bkt_start, bkt_cur);
    binscatter_k<<<(N_EDGES + EPB - 1) / EPB, 256, 0, stream>>>(ei, bkt_cur, pairs);
    bucket_csr_k<<<NBKT, 256, 0, stream>>>(pairs, bkt_start, starts, cnt, dis, srclist);

    // h1 = elu(x @ nfc_w^T + nfc_b)                       [100k,64]x[64,128] fp32 out
    gemm_k<64, 128, 64, 4, 8, true, false, true, false>
        <<<(N_NODES + 63) / 64, 256, 0, stream>>>(x, nfc_w, nfc_b, dis, h1, N_NODES);
    // c1 = dis * (h1 @ g1bw^T)   -> bf16                  [100k,128]x[128,64]
    gemm_k<128, 64, 32, 2, 4, false, true, false, true>
        <<<(N_NODES + 31) / 32, 256, 0, stream>>>(h1, g1bw, nullptr, dis, (float*)c1, N_NODES);
    // w1 = h1 @ g1cw^T + g1cb                             [100k,128]x[128,32] fp32
    gemm_k<128, 32, 64, 4, 2, false, false, true, false>
        <<<(N_NODES + 63) / 64, 256, 0, stream>>>(h1, g1cw, g1cb, dis, w1, N_NODES);
    // h2 = elu(dis * combine(w1, gather(c1)) + g1_bias)  -> h1 buffer
    gather1_k<<<N_NODES / 16, 256, 0, stream>>>(starts, cnt, srclist, c1, w1, dis, g1b, h1);
    // w2 = h2 @ g2cw^T + g2cb  (before c2 overwrites c1 region is fine; w2 separate)
    gemm_k<128, 32, 64, 4, 2, false, false, true, false>
        <<<(N_NODES + 63) / 64, 256, 0, stream>>>(h1, g2cw, g2cb, dis, w2, N_NODES);
    // c2 = dis * (h2 @ g2bw^T)  -> bf16
    gemm_k<128, 32, 64, 4, 2, false, true, false, true>
        <<<(N_NODES + 63) / 64, 256, 0, stream>>>(h1, g2bw, nullptr, dis, (float*)c2, N_NODES);
    // h = normalize(elu(dis * combine(w2, gather(c2)) + g2_bias))
    gather2_k<<<N_NODES / 16, 256, 0, stream>>>(starts, cnt, srclist, c2, w2, dis, g2b, hout);
    // per-graph pooling + attention heads
    graph_k<<<N_GRAPHS, 128, 0, stream>>>(hout, z_e, aw, ab, fcgw, fcgb, fccgw, fccgb, z_a, z_c);
}

// Round 8
// 335.284 us; speedup vs baseline: 1.9995x; 1.3688x over previous
//
#include <hip/hip_runtime.h>
#include <hip/hip_bf16.h>
#include <math.h>

#define N_NODES  100000
#define N_EDGES  1600000
#define N_GRAPHS 1000
#define NPG      100
#define NBKT     391          // ceil(100000/256); bucket = dst >> 8
#define EPB      4096         // edges per block in binning kernels

typedef float  f32x4 __attribute__((ext_vector_type(4)));
typedef short  s16x8 __attribute__((ext_vector_type(8)));

__device__ __forceinline__ float elu_f(float x) {
    return x > 0.0f ? x : expm1f(x);
}
__device__ __forceinline__ float bf2f(unsigned int u16) {
    union { unsigned int i; float f; } v; v.i = u16 << 16; return v.f;
}
__device__ __forceinline__ unsigned short f2bf(float f) {
    __hip_bfloat16 h = __float2bfloat16(f);
    return *reinterpret_cast<unsigned short*>(&h);
}

__device__ __forceinline__ s16x8 cvt8(const float4& a, const float4& b) {
    s16x8 o;
    o[0]=(short)f2bf(a.x); o[1]=(short)f2bf(a.y); o[2]=(short)f2bf(a.z); o[3]=(short)f2bf(a.w);
    o[4]=(short)f2bf(b.x); o[5]=(short)f2bf(b.y); o[6]=(short)f2bf(b.z); o[7]=(short)f2bf(b.w);
    return o;
}
__device__ __forceinline__ void split8(const float4& a, const float4& b, s16x8& hi, s16x8& lo) {
#define SP(i, val) { unsigned short h_ = f2bf(val); hi[i] = (short)h_; lo[i] = (short)f2bf((val) - bf2f(h_)); }
    SP(0, a.x) SP(1, a.y) SP(2, a.z) SP(3, a.w)
    SP(4, b.x) SP(5, b.y) SP(6, b.z) SP(7, b.w)
#undef SP
}
__device__ __forceinline__ void unpack8(const uint4& a, const uint4& b, s16x8& hi, s16x8& lo) {
#define UP(i, u) { hi[i] = (short)((u) >> 16); lo[i] = (short)((u) & 0xffffu); }
    UP(0, a.x) UP(1, a.y) UP(2, a.z) UP(3, a.w)
    UP(4, b.x) UP(5, b.y) UP(6, b.z) UP(7, b.w)
#undef UP
}

// ---------------- binned CSR build ----------------
__global__ __launch_bounds__(512) void zero_bkt_k(int* __restrict__ bkt_cnt) {
    int t = threadIdx.x;
    if (t < NBKT) bkt_cnt[t] = 0;
}

__global__ __launch_bounds__(256) void bincount_k(const int* __restrict__ ei, int* __restrict__ bkt_cnt) {
    __shared__ int h[NBKT];
    const int t = threadIdx.x;
    for (int i = t; i < NBKT; i += 256) h[i] = 0;
    __syncthreads();
    const int4* dst4 = (const int4*)(ei + N_EDGES);
    int i0 = blockIdx.x * (EPB / 4);
    for (int i = t; i < EPB / 4; i += 256) {
        int g = i0 + i;
        if (g < N_EDGES / 4) {
            int4 d = dst4[g];
            atomicAdd(&h[d.x >> 8], 1);
            atomicAdd(&h[d.y >> 8], 1);
            atomicAdd(&h[d.z >> 8], 1);
            atomicAdd(&h[d.w >> 8], 1);
        }
    }
    __syncthreads();
    for (int i = t; i < NBKT; i += 256)
        if (h[i]) atomicAdd(&bkt_cnt[i], h[i]);
}

__global__ __launch_bounds__(512) void bkt_scan_k(const int* __restrict__ bkt_cnt,
                                                  int* __restrict__ bkt_start,
                                                  int* __restrict__ bkt_cursor)
{
    __shared__ int s[512];
    int t = threadIdx.x;
    s[t] = (t < NBKT) ? bkt_cnt[t] : 0;
    __syncthreads();
    #pragma unroll
    for (int off = 1; off < 512; off <<= 1) {
        int u = (t >= off) ? s[t - off] : 0;
        __syncthreads();
        s[t] += u;
        __syncthreads();
    }
    if (t <= NBKT) {
        int v = (t == 0) ? 0 : s[t - 1];
        bkt_start[t] = v;
        if (t < NBKT) bkt_cursor[t] = v;
    }
}

__global__ __launch_bounds__(256) void binscatter_k(const int* __restrict__ ei,
                                                    int* __restrict__ bkt_cursor,
                                                    int2* __restrict__ pairs)
{
    __shared__ int h[NBKT];
    __shared__ int base[NBKT];
    const int t = threadIdx.x;
    for (int i = t; i < NBKT; i += 256) h[i] = 0;
    __syncthreads();
    const int4* src4 = (const int4*)ei;
    const int4* dst4 = (const int4*)(ei + N_EDGES);
    int i0 = blockIdx.x * (EPB / 4);
    for (int i = t; i < EPB / 4; i += 256) {
        int g = i0 + i;
        if (g < N_EDGES / 4) {
            int4 d = dst4[g];
            atomicAdd(&h[d.x >> 8], 1);
            atomicAdd(&h[d.y >> 8], 1);
            atomicAdd(&h[d.z >> 8], 1);
            atomicAdd(&h[d.w >> 8], 1);
        }
    }
    __syncthreads();
    for (int i = t; i < NBKT; i += 256) {
        int c = h[i];
        base[i] = c ? atomicAdd(&bkt_cursor[i], c) : 0;
        h[i] = 0;
    }
    __syncthreads();
    for (int i = t; i < EPB / 4; i += 256) {
        int g = i0 + i;
        if (g < N_EDGES / 4) {
            int4 s4 = src4[g];
            int4 d4 = dst4[g];
            int b, r;
            b = d4.x >> 8; r = atomicAdd(&h[b], 1); pairs[base[b] + r] = make_int2(s4.x, d4.x);
            b = d4.y >> 8; r = atomicAdd(&h[b], 1); pairs[base[b] + r] = make_int2(s4.y, d4.y);
            b = d4.z >> 8; r = atomicAdd(&h[b], 1); pairs[base[b] + r] = make_int2(s4.z, d4.z);
            b = d4.w >> 8; r = atomicAdd(&h[b], 1); pairs[base[b] + r] = make_int2(s4.w, d4.w);
        }
    }
}

__global__ __launch_bounds__(256) void bucket_csr_k(const int2* __restrict__ pairs,
                                                    const int* __restrict__ bkt_start,
                                                    int* __restrict__ starts,
                                                    int* __restrict__ cnt,
                                                    float* __restrict__ dis,
                                                    int* __restrict__ srclist)
{
    __shared__ int s[256];
    __shared__ int cur[256];
    const int b = blockIdx.x, t = threadIdx.x;
    const int lo = bkt_start[b], hi = bkt_start[b + 1];
    const int n0 = b << 8;
    const int nn = min(256, N_NODES - n0);

    s[t] = 0;
    __syncthreads();
    for (int i = lo + t; i < hi; i += 256) {
        int2 p = pairs[i];
        atomicAdd(&s[p.y & 255], 1);
    }
    __syncthreads();
    int v = s[t];
    __syncthreads();
    s[t] = v;
    __syncthreads();
    #pragma unroll
    for (int off = 1; off < 256; off <<= 1) {
        int u = (t >= off) ? s[t - off] : 0;
        __syncthreads();
        s[t] += u;
        __syncthreads();
    }
    int ex = lo + s[t] - v;
    if (t < nn) {
        starts[n0 + t] = ex;
        cnt[n0 + t] = v;
        dis[n0 + t] = rsqrtf(1.0f + (float)v);
    }
    cur[t] = ex;
    __syncthreads();
    for (int i = lo + t; i < hi; i += 256) {
        int2 p = pairs[i];
        int pos = atomicAdd(&cur[p.y & 255], 1);
        srclist[pos] = p.x;
    }
}

// ---------------- MFMA GEMM: out = post(A[M,K] @ W[N,K]^T) ----------------
// A either fp32 (AF32, split to hi/lo bf16 on the fly) or packed split uint (hi<<16|lo).
// EP: 0 = +bias, elu, split-pack uint out; 1 = *dis, bf16 out; 2 = +bias, fp32 out.
// No LDS: direct global->reg fragments (A rows and W rows both contiguous along K).
template<int K, int N, int WR, int WC, int RT, int CT, int EP, bool AF32>
__global__ __launch_bounds__(256) void mgemm_k(
    const void* __restrict__ Av, const float* __restrict__ W,
    const float* __restrict__ bias, const float* __restrict__ dis,
    void* __restrict__ outv, int M)
{
    constexpr int KT = K / 32;
    const int t = threadIdx.x;
    const int wave = t >> 6, lane = t & 63;
    const int wr = wave / WC, wc = wave % WC;
    const int lr = lane & 15, lk = lane >> 4;
    const int blockRow = blockIdx.x * (WR * RT * 16);

    f32x4 acc[RT][CT];
    #pragma unroll
    for (int rt = 0; rt < RT; ++rt)
        #pragma unroll
        for (int ct = 0; ct < CT; ++ct)
            acc[rt][ct] = (f32x4){0.f, 0.f, 0.f, 0.f};

    const float*        Af = (const float*)Av;
    const unsigned int* Au = (const unsigned int*)Av;

    #pragma unroll
    for (int kt = 0; kt < KT; ++kt) {
        const int k0 = kt * 32 + lk * 8;
        s16x8 ahi[RT], alo[RT];
        #pragma unroll
        for (int rt = 0; rt < RT; ++rt) {
            int r = blockRow + (wr * RT + rt) * 16 + lr;
            r = (r < M) ? r : (M - 1);
            if constexpr (AF32) {
                const float* ap = Af + (size_t)r * K + k0;
                float4 v1 = *(const float4*)ap;
                float4 v2 = *(const float4*)(ap + 4);
                split8(v1, v2, ahi[rt], alo[rt]);
            } else {
                const unsigned int* ap = Au + (size_t)r * K + k0;
                uint4 u1 = *(const uint4*)ap;
                uint4 u2 = *(const uint4*)(ap + 4);
                unpack8(u1, u2, ahi[rt], alo[rt]);
            }
        }
        s16x8 bfr[CT];
        #pragma unroll
        for (int ct = 0; ct < CT; ++ct) {
            int n = (wc * CT + ct) * 16 + lr;
            const float* wp = W + (size_t)n * K + k0;
            float4 v1 = *(const float4*)wp;
            float4 v2 = *(const float4*)(wp + 4);
            bfr[ct] = cvt8(v1, v2);
        }
        #pragma unroll
        for (int rt = 0; rt < RT; ++rt)
            #pragma unroll
            for (int ct = 0; ct < CT; ++ct) {
                acc[rt][ct] = __builtin_amdgcn_mfma_f32_16x16x32_bf16(ahi[rt], bfr[ct], acc[rt][ct], 0, 0, 0);
                acc[rt][ct] = __builtin_amdgcn_mfma_f32_16x16x32_bf16(alo[rt], bfr[ct], acc[rt][ct], 0, 0, 0);
            }
    }

    // epilogue: D[m = 4*lk + j + tile][n = lr + tile]
    #pragma unroll
    for (int rt = 0; rt < RT; ++rt) {
        int mbase = blockRow + (wr * RT + rt) * 16 + lk * 4;
        #pragma unroll
        for (int j = 0; j < 4; ++j) {
            int m = mbase + j;
            if (m >= M) continue;
            float dsc = 1.0f;
            if constexpr (EP == 1) dsc = dis[m];
            #pragma unroll
            for (int ct = 0; ct < CT; ++ct) {
                int n = (wc * CT + ct) * 16 + lr;
                float v = acc[rt][ct][j];
                if constexpr (EP == 0) {
                    v += bias[n];
                    v = elu_f(v);
                    unsigned short h_ = f2bf(v);
                    unsigned short l_ = f2bf(v - bf2f(h_));
                    ((unsigned int*)outv)[(size_t)m * N + n] = ((unsigned int)h_ << 16) | l_;
                } else if constexpr (EP == 1) {
                    v *= dsc;
                    ((unsigned short*)outv)[(size_t)m * N + n] = f2bf(v);
                } else {
                    v += bias[n];
                    ((float*)outv)[(size_t)m * N + n] = v;
                }
            }
        }
    }
}

// ---------------- layer-1 gather + combine + elu (c bf16 in, h2 split-uint out) ----------------
__global__ __launch_bounds__(256) void gather1_k(
    const int* __restrict__ starts, const int* __restrict__ cnt,
    const int* __restrict__ srclist, const unsigned short* __restrict__ c,
    const float* __restrict__ w1, const float* __restrict__ dis,
    const float* __restrict__ bias, unsigned int* __restrict__ h2s)
{
    __shared__ float aggS[16][68];
    __shared__ float w1S[16][32];

    const int t = threadIdx.x;
    const int nn = t >> 4;
    const int q  = t & 15;
    const int n  = blockIdx.x * 16 + nn;

    {
        int i0 = t * 2;
        int wn = i0 >> 5, wj = i0 & 31;
        float2 v = *(const float2*)(w1 + (size_t)(blockIdx.x * 16 + wn) * 32 + wj);
        w1S[wn][wj] = v.x;
        w1S[wn][wj + 1] = v.y;
    }

    const int s0 = starts[n];
    const int cn = cnt[n];
    float a0, a1, a2, a3;
    {
        uint2 u = *(const uint2*)(c + (size_t)n * 64 + q * 4);
        a0 = bf2f(u.x & 0xffff); a1 = bf2f(u.x >> 16);
        a2 = bf2f(u.y & 0xffff); a3 = bf2f(u.y >> 16);
    }
    for (int j = 0; j < cn; ++j) {
        int src = srclist[s0 + j];
        uint2 u = *(const uint2*)(c + (size_t)src * 64 + q * 4);
        a0 += bf2f(u.x & 0xffff); a1 += bf2f(u.x >> 16);
        a2 += bf2f(u.y & 0xffff); a3 += bf2f(u.y >> 16);
    }
    aggS[nn][q * 4 + 0] = a0;
    aggS[nn][q * 4 + 1] = a1;
    aggS[nn][q * 4 + 2] = a2;
    aggS[nn][q * 4 + 3] = a3;
    __syncthreads();

    float ab[4];
    #pragma unroll
    for (int b = 0; b < 4; ++b) ab[b] = aggS[nn][b * 16 + q];
    const float dn = dis[n];
    unsigned int* out = h2s + (size_t)n * 128;
    #pragma unroll
    for (int r = 0; r < 8; ++r) {
        float s = 0.0f;
        #pragma unroll
        for (int b = 0; b < 4; ++b) s = fmaf(w1S[nn][r * 4 + b], ab[b], s);
        float v = elu_f(s * dn + bias[r * 16 + q]);
        unsigned short h_ = f2bf(v);
        unsigned short l_ = f2bf(v - bf2f(h_));
        out[r * 16 + q] = ((unsigned int)h_ << 16) | l_;
    }
}

// ---------------- layer-2 gather + combine + elu + L2 normalize (c bf16) ----------------
__global__ __launch_bounds__(256) void gather2_k(
    const int* __restrict__ starts, const int* __restrict__ cnt,
    const int* __restrict__ srclist, const unsigned short* __restrict__ c,
    const float* __restrict__ w2, const float* __restrict__ dis,
    const float* __restrict__ bias, float* __restrict__ hout)
{
    __shared__ float aggS[16][36];
    __shared__ float w2S[16][32];

    const int t = threadIdx.x;
    const int nn = t >> 4;
    const int q  = t & 15;
    const int n  = blockIdx.x * 16 + nn;

    {
        int i0 = t * 2;
        int wn = i0 >> 5, wj = i0 & 31;
        float2 v = *(const float2*)(w2 + (size_t)(blockIdx.x * 16 + wn) * 32 + wj);
        w2S[wn][wj] = v.x;
        w2S[wn][wj + 1] = v.y;
    }

    const int s0 = starts[n];
    const int cn = cnt[n];
    float a0, a1;
    {
        unsigned int u = *(const unsigned int*)(c + (size_t)n * 32 + q * 2);
        a0 = bf2f(u & 0xffff); a1 = bf2f(u >> 16);
    }
    for (int j = 0; j < cn; ++j) {
        int src = srclist[s0 + j];
        unsigned int u = *(const unsigned int*)(c + (size_t)src * 32 + q * 2);
        a0 += bf2f(u & 0xffff); a1 += bf2f(u >> 16);
    }
    aggS[nn][q * 2 + 0] = a0;
    aggS[nn][q * 2 + 1] = a1;
    __syncthreads();

    const float dn = dis[n];
    float sv[4];
    #pragma unroll
    for (int r = 0; r < 4; ++r) {
        int j = r * 16 + q;
        int hh = j >> 3, f = j & 7;
        float s = 0.0f;
        #pragma unroll
        for (int b = 0; b < 4; ++b) s = fmaf(w2S[nn][hh * 4 + b], aggS[nn][b * 8 + f], s);
        sv[r] = elu_f(s * dn + bias[j]);
    }

    float tot = sv[0]*sv[0] + sv[1]*sv[1] + sv[2]*sv[2] + sv[3]*sv[3];
    #pragma unroll
    for (int o = 1; o < 16; o <<= 1) tot += __shfl_xor(tot, o, 64);
    float inv = 1.0f / fmaxf(sqrtf(tot), 1e-12f);
    float* out = hout + (size_t)n * 64;
    #pragma unroll
    for (int r = 0; r < 4; ++r) out[r * 16 + q] = sv[r] * inv;
}

// ---------------- per-graph tail: z_a, attention softmax, z_c ----------------
__global__ __launch_bounds__(128) void graph_k(const float* __restrict__ h,
                                               const float* __restrict__ z_e,
                                               const float* __restrict__ aw,
                                               const float* __restrict__ ab,
                                               const float* __restrict__ fcgw,
                                               const float* __restrict__ fcgb,
                                               const float* __restrict__ fccgw,
                                               const float* __restrict__ fccgb,
                                               float* __restrict__ z_a,
                                               float* __restrict__ z_c)
{
    __shared__ float Hs[NPG * 64];
    __shared__ float sumh[64], wsh[64], lg[NPG], ex[NPG];
    __shared__ float red[2];
    int g = blockIdx.x, t = threadIdx.x;
    const float* hg = h + (size_t)g * NPG * 64;
    for (int idx = t; idx < NPG * 64; idx += 128) Hs[idx] = hg[idx];
    __syncthreads();

    if (t < 64) {
        float s = 0.0f;
        for (int n = 0; n < NPG; ++n) s += Hs[n * 64 + t];
        sumh[t] = s;
    }
    __syncthreads();

    if (t < 64) {
        float acc = fcgb[t];
        for (int f = 0; f < 64; ++f) acc = fmaf(sumh[f], fcgw[t * 64 + f], acc);
        z_a[(size_t)g * 64 + t] = acc;
    }
    if (t < NPG) {
        float zd = 0.0f;
        for (int q = 0; q < 32; ++q) zd = fmaf(z_e[(size_t)g * 32 + q], aw[64 + q], zd);
        float dot = 0.0f;
        for (int k0 = 0; k0 < 64; ++k0) {
            int k = (k0 + t) & 63;
            dot = fmaf(Hs[t * 64 + k], aw[k], dot);
        }
        lg[t] = dot + zd + ab[0] + 1e-16f;
    }
    __syncthreads();

    if (t < 64) {
        float m = -INFINITY;
        for (int n = t; n < NPG; n += 64) m = fmaxf(m, lg[n]);
        #pragma unroll
        for (int o = 1; o < 64; o <<= 1) m = fmaxf(m, __shfl_xor(m, o, 64));
        if (t == 0) red[0] = m;
    }
    __syncthreads();
    float m = red[0];
    if (t < NPG) ex[t] = expf(lg[t] - m);
    __syncthreads();
    if (t < 64) {
        float s = 0.0f;
        for (int n = t; n < NPG; n += 64) s += ex[n];
        #pragma unroll
        for (int o = 1; o < 64; o <<= 1) s += __shfl_xor(s, o, 64);
        if (t == 0) red[1] = s + 1e-16f;
    }
    __syncthreads();
    float inv_denom = 1.0f / red[1];
    if (t < 64) {
        float a = 0.0f;
        for (int n = 0; n < NPG; ++n) a = fmaf(ex[n], Hs[n * 64 + t], a);
        wsh[t] = a * inv_denom;
    }
    __syncthreads();
    if (t < 64) {
        float acc = fccgb[t];
        for (int f = 0; f < 64; ++f) acc = fmaf(wsh[f], fccgw[t * 64 + f], acc);
        z_c[(size_t)g * 64 + t] = acc;
    }
}

extern "C" void kernel_launch(void* const* d_in, const int* in_sizes, int n_in,
                              void* d_out, int out_size, void* d_ws, size_t ws_size,
                              hipStream_t stream)
{
    const float* x     = (const float*)d_in[0];
    const int*   ei    = (const int*)d_in[1];
    const float* z_e   = (const float*)d_in[4];
    const float* nfc_w = (const float*)d_in[5];
    const float* nfc_b = (const float*)d_in[6];
    const float* g1bw  = (const float*)d_in[7];
    const float* g1cw  = (const float*)d_in[8];
    const float* g1cb  = (const float*)d_in[9];
    const float* g1b   = (const float*)d_in[10];
    const float* g2bw  = (const float*)d_in[11];
    const float* g2cw  = (const float*)d_in[12];
    const float* g2cb  = (const float*)d_in[13];
    const float* g2b   = (const float*)d_in[14];
    const float* aw    = (const float*)d_in[15];
    const float* ab    = (const float*)d_in[16];
    const float* fcgw  = (const float*)d_in[17];
    const float* fcgb  = (const float*)d_in[18];
    const float* fccgw = (const float*)d_in[19];
    const float* fccgb = (const float*)d_in[20];

    // workspace layout (~90 MB)
    float* ws        = (float*)d_ws;
    float* dis       = ws;                           // 102400 fl
    int*   cnt       = (int*)(ws + 102400);          // 102400
    int*   starts    = cnt + 102400;                 // 102400
    int*   bkt_cnt   = starts + 102400;              // 512
    int*   bkt_start = bkt_cnt + 512;                // 512
    int*   bkt_cur   = bkt_start + 512;              // 512
    int*   srclist   = bkt_cur + 512;                // 1,600,000
    float* hbuf      = (float*)(srclist + 1600000);  // 12.8M words: h1s/h2s packed split uint
    float* c1f       = hbuf + 12800000;              // c region (bf16): c1 6.4M bf16 / c2 aliased
    float* w1        = c1f + 3200000;                // 3.2M fl
    float* w2        = w1 + 3200000;                 // 3.2M fl
    unsigned int*   hs = (unsigned int*)hbuf;        // [100k x 128] packed hi|lo
    unsigned short* c1 = (unsigned short*)c1f;       // [100k x 64] bf16
    unsigned short* c2 = (unsigned short*)c1f;       // [100k x 32] bf16 (c1 dead by then)
    int2*  pairs     = (int2*)hbuf;                  // 12.8MB, dead before hs written

    float* z_a  = (float*)d_out;
    float* z_c  = z_a + (size_t)N_GRAPHS * 64;
    float* hout = z_a + (size_t)2 * N_GRAPHS * 64;

    const int GB = (N_NODES + 63) / 64;   // 1563 blocks of 64 rows

    // binned CSR build
    zero_bkt_k<<<1, 512, 0, stream>>>(bkt_cnt);
    bincount_k<<<(N_EDGES + EPB - 1) / EPB, 256, 0, stream>>>(ei, bkt_cnt);
    bkt_scan_k<<<1, 512, 0, stream>>>(bkt_cnt, bkt_start, bkt_cur);
    binscatter_k<<<(N_EDGES + EPB - 1) / EPB, 256, 0, stream>>>(ei, bkt_cur, pairs);
    bucket_csr_k<<<NBKT, 256, 0, stream>>>(pairs, bkt_start, starts, cnt, dis, srclist);

    // h1 = elu(x @ nfc_w^T + b) -> split uint              [100k,64]x[64,128]
    mgemm_k<64, 128, 2, 2, 2, 4, 0, true>
        <<<GB, 256, 0, stream>>>(x, nfc_w, nfc_b, dis, hs, N_NODES);
    // c1 = dis * (h1 @ g1bw^T) -> bf16                     [100k,128]x[128,64]
    mgemm_k<128, 64, 2, 2, 2, 2, 1, false>
        <<<GB, 256, 0, stream>>>(hs, g1bw, nullptr, dis, c1, N_NODES);
    // w1 = h1 @ g1cw^T + g1cb -> fp32                      [100k,128]x[128,32]
    mgemm_k<128, 32, 4, 1, 1, 2, 2, false>
        <<<GB, 256, 0, stream>>>(hs, g1cw, g1cb, dis, w1, N_NODES);
    // h2 = elu(dis * combine(w1, gather(c1)) + g1_bias) -> split uint (hs buffer)
    gather1_k<<<N_NODES / 16, 256, 0, stream>>>(starts, cnt, srclist, c1, w1, dis, g1b, hs);
    // w2 = h2 @ g2cw^T + g2cb -> fp32
    mgemm_k<128, 32, 4, 1, 1, 2, 2, false>
        <<<GB, 256, 0, stream>>>(hs, g2cw, g2cb, dis, w2, N_NODES);
    // c2 = dis * (h2 @ g2bw^T) -> bf16
    mgemm_k<128, 32, 4, 1, 1, 2, 1, false>
        <<<GB, 256, 0, stream>>>(hs, g2bw, nullptr, dis, c2, N_NODES);
    // h = normalize(elu(dis * combine(w2, gather(c2)) + g2_bias))
    gather2_k<<<N_NODES / 16, 256, 0, stream>>>(starts, cnt, srclist, c2, w2, dis, g2b, hout);
    // per-graph pooling + attention heads
    graph_k<<<N_GRAPHS, 128, 0, stream>>>(hout, z_e, aw, ab, fcgw, fcgb, fccgw, fccgb, z_a, z_c);
}

// Round 9
// 333.234 us; speedup vs baseline: 2.0118x; 1.0061x over previous
//
#include <hip/hip_runtime.h>
#include <hip/hip_bf16.h>
#include <math.h>

#define N_NODES  100000
#define N_EDGES  1600000
#define N_GRAPHS 1000
#define NPG      100
#define NBKT     391          // ceil(100000/256); bucket = dst >> 8
#define EPB      4096         // edges per block in binning kernels

typedef float  f32x4 __attribute__((ext_vector_type(4)));
typedef short  s16x8 __attribute__((ext_vector_type(8)));

__device__ __forceinline__ float elu_f(float x) {
    return x > 0.0f ? x : expm1f(x);
}
__device__ __forceinline__ float bf2f(unsigned int u16) {
    union { unsigned int i; float f; } v; v.i = u16 << 16; return v.f;
}
__device__ __forceinline__ unsigned short f2bf(float f) {
    __hip_bfloat16 h = __float2bfloat16(f);
    return *reinterpret_cast<unsigned short*>(&h);
}

__device__ __forceinline__ s16x8 cvt8(const float4& a, const float4& b) {
    s16x8 o;
    o[0]=(short)f2bf(a.x); o[1]=(short)f2bf(a.y); o[2]=(short)f2bf(a.z); o[3]=(short)f2bf(a.w);
    o[4]=(short)f2bf(b.x); o[5]=(short)f2bf(b.y); o[6]=(short)f2bf(b.z); o[7]=(short)f2bf(b.w);
    return o;
}
__device__ __forceinline__ void split8(const float4& a, const float4& b, s16x8& hi, s16x8& lo) {
#define SP(i, val) { unsigned short h_ = f2bf(val); hi[i] = (short)h_; lo[i] = (short)f2bf((val) - bf2f(h_)); }
    SP(0, a.x) SP(1, a.y) SP(2, a.z) SP(3, a.w)
    SP(4, b.x) SP(5, b.y) SP(6, b.z) SP(7, b.w)
#undef SP
}
__device__ __forceinline__ void unpack8(const uint4& a, const uint4& b, s16x8& hi, s16x8& lo) {
#define UP(i, u) { hi[i] = (short)((u) >> 16); lo[i] = (short)((u) & 0xffffu); }
    UP(0, a.x) UP(1, a.y) UP(2, a.z) UP(3, a.w)
    UP(4, b.x) UP(5, b.y) UP(6, b.z) UP(7, b.w)
#undef UP
}

// ---------------- binned CSR build ----------------
__global__ __launch_bounds__(512) void zero_bkt_k(int* __restrict__ bkt_cnt) {
    int t = threadIdx.x;
    if (t < NBKT) bkt_cnt[t] = 0;
}

__global__ __launch_bounds__(256) void bincount_k(const int* __restrict__ ei, int* __restrict__ bkt_cnt) {
    __shared__ int h[NBKT];
    const int t = threadIdx.x;
    for (int i = t; i < NBKT; i += 256) h[i] = 0;
    __syncthreads();
    const int4* dst4 = (const int4*)(ei + N_EDGES);
    int i0 = blockIdx.x * (EPB / 4);
    for (int i = t; i < EPB / 4; i += 256) {
        int g = i0 + i;
        if (g < N_EDGES / 4) {
            int4 d = dst4[g];
            atomicAdd(&h[d.x >> 8], 1);
            atomicAdd(&h[d.y >> 8], 1);
            atomicAdd(&h[d.z >> 8], 1);
            atomicAdd(&h[d.w >> 8], 1);
        }
    }
    __syncthreads();
    for (int i = t; i < NBKT; i += 256)
        if (h[i]) atomicAdd(&bkt_cnt[i], h[i]);
}

__global__ __launch_bounds__(512) void bkt_scan_k(const int* __restrict__ bkt_cnt,
                                                  int* __restrict__ bkt_start,
                                                  int* __restrict__ bkt_cursor)
{
    __shared__ int s[512];
    int t = threadIdx.x;
    s[t] = (t < NBKT) ? bkt_cnt[t] : 0;
    __syncthreads();
    #pragma unroll
    for (int off = 1; off < 512; off <<= 1) {
        int u = (t >= off) ? s[t - off] : 0;
        __syncthreads();
        s[t] += u;
        __syncthreads();
    }
    if (t <= NBKT) {
        int v = (t == 0) ? 0 : s[t - 1];
        bkt_start[t] = v;
        if (t < NBKT) bkt_cursor[t] = v;
    }
}

__global__ __launch_bounds__(256) void binscatter_k(const int* __restrict__ ei,
                                                    int* __restrict__ bkt_cursor,
                                                    int2* __restrict__ pairs)
{
    __shared__ int h[NBKT];
    __shared__ int base[NBKT];
    const int t = threadIdx.x;
    for (int i = t; i < NBKT; i += 256) h[i] = 0;
    __syncthreads();
    const int4* src4 = (const int4*)ei;
    const int4* dst4 = (const int4*)(ei + N_EDGES);
    int i0 = blockIdx.x * (EPB / 4);
    for (int i = t; i < EPB / 4; i += 256) {
        int g = i0 + i;
        if (g < N_EDGES / 4) {
            int4 d = dst4[g];
            atomicAdd(&h[d.x >> 8], 1);
            atomicAdd(&h[d.y >> 8], 1);
            atomicAdd(&h[d.z >> 8], 1);
            atomicAdd(&h[d.w >> 8], 1);
        }
    }
    __syncthreads();
    for (int i = t; i < NBKT; i += 256) {
        int c = h[i];
        base[i] = c ? atomicAdd(&bkt_cursor[i], c) : 0;
        h[i] = 0;
    }
    __syncthreads();
    for (int i = t; i < EPB / 4; i += 256) {
        int g = i0 + i;
        if (g < N_EDGES / 4) {
            int4 s4 = src4[g];
            int4 d4 = dst4[g];
            int b, r;
            b = d4.x >> 8; r = atomicAdd(&h[b], 1); pairs[base[b] + r] = make_int2(s4.x, d4.x);
            b = d4.y >> 8; r = atomicAdd(&h[b], 1); pairs[base[b] + r] = make_int2(s4.y, d4.y);
            b = d4.z >> 8; r = atomicAdd(&h[b], 1); pairs[base[b] + r] = make_int2(s4.z, d4.z);
            b = d4.w >> 8; r = atomicAdd(&h[b], 1); pairs[base[b] + r] = make_int2(s4.w, d4.w);
        }
    }
}

__global__ __launch_bounds__(256) void bucket_csr_k(const int2* __restrict__ pairs,
                                                    const int* __restrict__ bkt_start,
                                                    int* __restrict__ starts,
                                                    int* __restrict__ cnt,
                                                    float* __restrict__ dis,
                                                    int* __restrict__ srclist)
{
    __shared__ int s[256];
    __shared__ int cur[256];
    const int b = blockIdx.x, t = threadIdx.x;
    const int lo = bkt_start[b], hi = bkt_start[b + 1];
    const int n0 = b << 8;
    const int nn = min(256, N_NODES - n0);

    s[t] = 0;
    __syncthreads();
    for (int i = lo + t; i < hi; i += 256) {
        int2 p = pairs[i];
        atomicAdd(&s[p.y & 255], 1);
    }
    __syncthreads();
    int v = s[t];
    __syncthreads();
    s[t] = v;
    __syncthreads();
    #pragma unroll
    for (int off = 1; off < 256; off <<= 1) {
        int u = (t >= off) ? s[t - off] : 0;
        __syncthreads();
        s[t] += u;
        __syncthreads();
    }
    int ex = lo + s[t] - v;
    if (t < nn) {
        starts[n0 + t] = ex;
        cnt[n0 + t] = v;
        dis[n0 + t] = rsqrtf(1.0f + (float)v);
    }
    cur[t] = ex;
    __syncthreads();
    for (int i = lo + t; i < hi; i += 256) {
        int2 p = pairs[i];
        int pos = atomicAdd(&cur[p.y & 255], 1);
        srclist[pos] = p.x;
    }
}

// ---------------- MFMA GEMM: out = post(A[M,K] @ W[N,K]^T) ----------------
template<int K, int N, int WR, int WC, int RT, int CT, int EP, bool AF32>
__global__ __launch_bounds__(256) void mgemm_k(
    const void* __restrict__ Av, const float* __restrict__ W,
    const float* __restrict__ bias, const float* __restrict__ dis,
    void* __restrict__ outv, int M)
{
    constexpr int KT = K / 32;
    const int t = threadIdx.x;
    const int wave = t >> 6, lane = t & 63;
    const int wr = wave / WC, wc = wave % WC;
    const int lr = lane & 15, lk = lane >> 4;
    const int blockRow = blockIdx.x * (WR * RT * 16);

    f32x4 acc[RT][CT];
    #pragma unroll
    for (int rt = 0; rt < RT; ++rt)
        #pragma unroll
        for (int ct = 0; ct < CT; ++ct)
            acc[rt][ct] = (f32x4){0.f, 0.f, 0.f, 0.f};

    const float*        Af = (const float*)Av;
    const unsigned int* Au = (const unsigned int*)Av;

    #pragma unroll
    for (int kt = 0; kt < KT; ++kt) {
        const int k0 = kt * 32 + lk * 8;
        s16x8 ahi[RT], alo[RT];
        #pragma unroll
        for (int rt = 0; rt < RT; ++rt) {
            int r = blockRow + (wr * RT + rt) * 16 + lr;
            r = (r < M) ? r : (M - 1);
            if constexpr (AF32) {
                const float* ap = Af + (size_t)r * K + k0;
                float4 v1 = *(const float4*)ap;
                float4 v2 = *(const float4*)(ap + 4);
                split8(v1, v2, ahi[rt], alo[rt]);
            } else {
                const unsigned int* ap = Au + (size_t)r * K + k0;
                uint4 u1 = *(const uint4*)ap;
                uint4 u2 = *(const uint4*)(ap + 4);
                unpack8(u1, u2, ahi[rt], alo[rt]);
            }
        }
        s16x8 bfr[CT];
        #pragma unroll
        for (int ct = 0; ct < CT; ++ct) {
            int n = (wc * CT + ct) * 16 + lr;
            const float* wp = W + (size_t)n * K + k0;
            float4 v1 = *(const float4*)wp;
            float4 v2 = *(const float4*)(wp + 4);
            bfr[ct] = cvt8(v1, v2);
        }
        #pragma unroll
        for (int rt = 0; rt < RT; ++rt)
            #pragma unroll
            for (int ct = 0; ct < CT; ++ct) {
                acc[rt][ct] = __builtin_amdgcn_mfma_f32_16x16x32_bf16(ahi[rt], bfr[ct], acc[rt][ct], 0, 0, 0);
                acc[rt][ct] = __builtin_amdgcn_mfma_f32_16x16x32_bf16(alo[rt], bfr[ct], acc[rt][ct], 0, 0, 0);
            }
    }

    #pragma unroll
    for (int rt = 0; rt < RT; ++rt) {
        int mbase = blockRow + (wr * RT + rt) * 16 + lk * 4;
        #pragma unroll
        for (int j = 0; j < 4; ++j) {
            int m = mbase + j;
            if (m >= M) continue;
            float dsc = 1.0f;
            if constexpr (EP == 1) dsc = dis[m];
            #pragma unroll
            for (int ct = 0; ct < CT; ++ct) {
                int n = (wc * CT + ct) * 16 + lr;
                float v = acc[rt][ct][j];
                if constexpr (EP == 0) {
                    v += bias[n];
                    v = elu_f(v);
                    unsigned short h_ = f2bf(v);
                    unsigned short l_ = f2bf(v - bf2f(h_));
                    ((unsigned int*)outv)[(size_t)m * N + n] = ((unsigned int)h_ << 16) | l_;
                } else if constexpr (EP == 1) {
                    v *= dsc;
                    ((unsigned short*)outv)[(size_t)m * N + n] = f2bf(v);
                } else {
                    v += bias[n];
                    ((float*)outv)[(size_t)m * N + n] = v;
                }
            }
        }
    }
}

// ---------------- layer-1 gather (wave/node, 4 edge slots) + combine + elu ----------------
// block = 256 = 4 nodes x 64 threads; lane = slot(4) x featquad(16)
__global__ __launch_bounds__(256) void gather1_k(
    const int* __restrict__ starts, const int* __restrict__ cnt,
    const int* __restrict__ srclist, const unsigned short* __restrict__ c,
    const float* __restrict__ w1, const float* __restrict__ dis,
    const float* __restrict__ bias, unsigned int* __restrict__ h2s)
{
    __shared__ float aggS[4][68];

    const int t = threadIdx.x;
    const int nn   = t >> 6;          // node within block
    const int lane = t & 63;
    const int q    = lane & 15;       // feature quad
    const int slot = lane >> 4;       // edge slot
    const int n    = blockIdx.x * 4 + nn;

    const int s0 = starts[n];
    const int cn = cnt[n];
    float a0 = 0.f, a1 = 0.f, a2 = 0.f, a3 = 0.f;
    if (slot == 0) {                  // self term
        uint2 u = *(const uint2*)(c + (size_t)n * 64 + q * 4);
        a0 = bf2f(u.x & 0xffff); a1 = bf2f(u.x >> 16);
        a2 = bf2f(u.y & 0xffff); a3 = bf2f(u.y >> 16);
    }
    for (int j = slot; j < cn; j += 4) {
        int src = srclist[s0 + j];
        uint2 u = *(const uint2*)(c + (size_t)src * 64 + q * 4);
        a0 += bf2f(u.x & 0xffff); a1 += bf2f(u.x >> 16);
        a2 += bf2f(u.y & 0xffff); a3 += bf2f(u.y >> 16);
    }
    // reduce across the 4 slots (lanes q, q+16, q+32, q+48) — wave converged here
    a0 += __shfl_xor(a0, 16, 64); a0 += __shfl_xor(a0, 32, 64);
    a1 += __shfl_xor(a1, 16, 64); a1 += __shfl_xor(a1, 32, 64);
    a2 += __shfl_xor(a2, 16, 64); a2 += __shfl_xor(a2, 32, 64);
    a3 += __shfl_xor(a3, 16, 64); a3 += __shfl_xor(a3, 32, 64);
    if (slot == 0) {
        aggS[nn][q * 4 + 0] = a0;
        aggS[nn][q * 4 + 1] = a1;
        aggS[nn][q * 4 + 2] = a2;
        aggS[nn][q * 4 + 3] = a3;
    }
    __syncthreads();

    // combine: lane computes outputs j = lane and j = lane + 64
    const float dn = dis[n];
    const float* wr = w1 + (size_t)n * 32;
    unsigned int* out = h2s + (size_t)n * 128;
    #pragma unroll
    for (int r = 0; r < 2; ++r) {
        int j = r * 64 + lane;
        int hh = j >> 4, f = j & 15;
        float4 wv = *(const float4*)(wr + hh * 4);
        float s = wv.x * aggS[nn][0 * 16 + f] + wv.y * aggS[nn][1 * 16 + f]
                + wv.z * aggS[nn][2 * 16 + f] + wv.w * aggS[nn][3 * 16 + f];
        float v = elu_f(s * dn + bias[j]);
        unsigned short h_ = f2bf(v);
        unsigned short l_ = f2bf(v - bf2f(h_));
        out[j] = ((unsigned int)h_ << 16) | l_;
    }
}

// ---------------- layer-2 gather (wave/node, 4 edge slots) + combine + elu + L2 norm ----------------
__global__ __launch_bounds__(256) void gather2_k(
    const int* __restrict__ starts, const int* __restrict__ cnt,
    const int* __restrict__ srclist, const unsigned short* __restrict__ c,
    const float* __restrict__ w2, const float* __restrict__ dis,
    const float* __restrict__ bias, float* __restrict__ hout)
{
    __shared__ float aggS[4][36];

    const int t = threadIdx.x;
    const int nn   = t >> 6;
    const int lane = t & 63;
    const int q    = lane & 15;       // feature pair
    const int slot = lane >> 4;
    const int n    = blockIdx.x * 4 + nn;

    const int s0 = starts[n];
    const int cn = cnt[n];
    float a0 = 0.f, a1 = 0.f;
    if (slot == 0) {                  // self term
        unsigned int u = *(const unsigned int*)(c + (size_t)n * 32 + q * 2);
        a0 = bf2f(u & 0xffff); a1 = bf2f(u >> 16);
    }
    for (int j = slot; j < cn; j += 4) {
        int src = srclist[s0 + j];
        unsigned int u = *(const unsigned int*)(c + (size_t)src * 32 + q * 2);
        a0 += bf2f(u & 0xffff); a1 += bf2f(u >> 16);
    }
    a0 += __shfl_xor(a0, 16, 64); a0 += __shfl_xor(a0, 32, 64);
    a1 += __shfl_xor(a1, 16, 64); a1 += __shfl_xor(a1, 32, 64);
    if (slot == 0) {
        aggS[nn][q * 2 + 0] = a0;
        aggS[nn][q * 2 + 1] = a1;
    }
    __syncthreads();

    // combine: lane computes output j = lane (64 outputs per node)
    const float dn = dis[n];
    const int hh = lane >> 3, f = lane & 7;
    float4 wv = *(const float4*)(w2 + (size_t)n * 32 + hh * 4);
    float s = wv.x * aggS[nn][0 * 8 + f] + wv.y * aggS[nn][1 * 8 + f]
            + wv.z * aggS[nn][2 * 8 + f] + wv.w * aggS[nn][3 * 8 + f];
    float sv = elu_f(s * dn + bias[lane]);

    float tot = sv * sv;
    #pragma unroll
    for (int o = 1; o < 64; o <<= 1) tot += __shfl_xor(tot, o, 64);
    float inv = 1.0f / fmaxf(sqrtf(tot), 1e-12f);
    hout[(size_t)n * 64 + lane] = sv * inv;
}

// ---------------- per-graph tail: z_a, attention softmax, z_c ----------------
__global__ __launch_bounds__(128) void graph_k(const float* __restrict__ h,
                                               const float* __restrict__ z_e,
                                               const float* __restrict__ aw,
                                               const float* __restrict__ ab,
                                               const float* __restrict__ fcgw,
                                               const float* __restrict__ fcgb,
                                               const float* __restrict__ fccgw,
                                               const float* __restrict__ fccgb,
                                               float* __restrict__ z_a,
                                               float* __restrict__ z_c)
{
    __shared__ float Hs[NPG * 64];
    __shared__ float sumh[64], wsh[64], lg[NPG], ex[NPG];
    __shared__ float red[2];
    int g = blockIdx.x, t = threadIdx.x;
    const float* hg = h + (size_t)g * NPG * 64;
    for (int idx = t; idx < NPG * 64; idx += 128) Hs[idx] = hg[idx];
    __syncthreads();

    if (t < 64) {
        float s = 0.0f;
        for (int n = 0; n < NPG; ++n) s += Hs[n * 64 + t];
        sumh[t] = s;
    }
    __syncthreads();

    if (t < 64) {
        float acc = fcgb[t];
        for (int f = 0; f < 64; ++f) acc = fmaf(sumh[f], fcgw[t * 64 + f], acc);
        z_a[(size_t)g * 64 + t] = acc;
    }
    if (t < NPG) {
        float zd = 0.0f;
        for (int q = 0; q < 32; ++q) zd = fmaf(z_e[(size_t)g * 32 + q], aw[64 + q], zd);
        float dot = 0.0f;
        for (int k0 = 0; k0 < 64; ++k0) {
            int k = (k0 + t) & 63;
            dot = fmaf(Hs[t * 64 + k], aw[k], dot);
        }
        lg[t] = dot + zd + ab[0] + 1e-16f;
    }
    __syncthreads();

    if (t < 64) {
        float m = -INFINITY;
        for (int n = t; n < NPG; n += 64) m = fmaxf(m, lg[n]);
        #pragma unroll
        for (int o = 1; o < 64; o <<= 1) m = fmaxf(m, __shfl_xor(m, o, 64));
        if (t == 0) red[0] = m;
    }
    __syncthreads();
    float m = red[0];
    if (t < NPG) ex[t] = expf(lg[t] - m);
    __syncthreads();
    if (t < 64) {
        float s = 0.0f;
        for (int n = t; n < NPG; n += 64) s += ex[n];
        #pragma unroll
        for (int o = 1; o < 64; o <<= 1) s += __shfl_xor(s, o, 64);
        if (t == 0) red[1] = s + 1e-16f;
    }
    __syncthreads();
    float inv_denom = 1.0f / red[1];
    if (t < 64) {
        float a = 0.0f;
        for (int n = 0; n < NPG; ++n) a = fmaf(ex[n], Hs[n * 64 + t], a);
        wsh[t] = a * inv_denom;
    }
    __syncthreads();
    if (t < 64) {
        float acc = fccgb[t];
        for (int f = 0; f < 64; ++f) acc = fmaf(wsh[f], fccgw[t * 64 + f], acc);
        z_c[(size_t)g * 64 + t] = acc;
    }
}

extern "C" void kernel_launch(void* const* d_in, const int* in_sizes, int n_in,
                              void* d_out, int out_size, void* d_ws, size_t ws_size,
                              hipStream_t stream)
{
    const float* x     = (const float*)d_in[0];
    const int*   ei    = (const int*)d_in[1];
    const float* z_e   = (const float*)d_in[4];
    const float* nfc_w = (const float*)d_in[5];
    const float* nfc_b = (const float*)d_in[6];
    const float* g1bw  = (const float*)d_in[7];
    const float* g1cw  = (const float*)d_in[8];
    const float* g1cb  = (const float*)d_in[9];
    const float* g1b   = (const float*)d_in[10];
    const float* g2bw  = (const float*)d_in[11];
    const float* g2cw  = (const float*)d_in[12];
    const float* g2cb  = (const float*)d_in[13];
    const float* g2b   = (const float*)d_in[14];
    const float* aw    = (const float*)d_in[15];
    const float* ab    = (const float*)d_in[16];
    const float* fcgw  = (const float*)d_in[17];
    const float* fcgb  = (const float*)d_in[18];
    const float* fccgw = (const float*)d_in[19];
    const float* fccgb = (const float*)d_in[20];

    // workspace layout (~90 MB)
    float* ws        = (float*)d_ws;
    float* dis       = ws;                           // 102400 fl
    int*   cnt       = (int*)(ws + 102400);          // 102400
    int*   starts    = cnt + 102400;                 // 102400
    int*   bkt_cnt   = starts + 102400;              // 512
    int*   bkt_start = bkt_cnt + 512;                // 512
    int*   bkt_cur   = bkt_start + 512;              // 512
    int*   srclist   = bkt_cur + 512;                // 1,600,000
    float* hbuf      = (float*)(srclist + 1600000);  // 12.8M words: h1s/h2s packed split uint
    float* c1f       = hbuf + 12800000;              // c region (bf16)
    float* w1        = c1f + 3200000;                // 3.2M fl
    float* w2        = w1 + 3200000;                 // 3.2M fl
    unsigned int*   hs = (unsigned int*)hbuf;        // [100k x 128] packed hi|lo
    unsigned short* c1 = (unsigned short*)c1f;       // [100k x 64] bf16
    unsigned short* c2 = (unsigned short*)c1f;       // [100k x 32] bf16 (c1 dead by then)
    int2*  pairs     = (int2*)hbuf;                  // 12.8MB, dead before hs written

    float* z_a  = (float*)d_out;
    float* z_c  = z_a + (size_t)N_GRAPHS * 64;
    float* hout = z_a + (size_t)2 * N_GRAPHS * 64;

    const int GB = (N_NODES + 63) / 64;   // 1563 blocks of 64 rows

    // binned CSR build
    zero_bkt_k<<<1, 512, 0, stream>>>(bkt_cnt);
    bincount_k<<<(N_EDGES + EPB - 1) / EPB, 256, 0, stream>>>(ei, bkt_cnt);
    bkt_scan_k<<<1, 512, 0, stream>>>(bkt_cnt, bkt_start, bkt_cur);
    binscatter_k<<<(N_EDGES + EPB - 1) / EPB, 256, 0, stream>>>(ei, bkt_cur, pairs);
    bucket_csr_k<<<NBKT, 256, 0, stream>>>(pairs, bkt_start, starts, cnt, dis, srclist);

    // h1 = elu(x @ nfc_w^T + b) -> split uint              [100k,64]x[64,128]
    mgemm_k<64, 128, 2, 2, 2, 4, 0, true>
        <<<GB, 256, 0, stream>>>(x, nfc_w, nfc_b, dis, hs, N_NODES);
    // c1 = dis * (h1 @ g1bw^T) -> bf16                     [100k,128]x[128,64]
    mgemm_k<128, 64, 2, 2, 2, 2, 1, false>
        <<<GB, 256, 0, stream>>>(hs, g1bw, nullptr, dis, c1, N_NODES);
    // w1 = h1 @ g1cw^T + g1cb -> fp32                      [100k,128]x[128,32]
    mgemm_k<128, 32, 4, 1, 1, 2, 2, false>
        <<<GB, 256, 0, stream>>>(hs, g1cw, g1cb, dis, w1, N_NODES);
    // h2 = elu(dis * combine(w1, gather(c1)) + g1_bias) -> split uint (hs buffer)
    gather1_k<<<N_NODES / 4, 256, 0, stream>>>(starts, cnt, srclist, c1, w1, dis, g1b, hs);
    // w2 = h2 @ g2cw^T + g2cb -> fp32
    mgemm_k<128, 32, 4, 1, 1, 2, 2, false>
        <<<GB, 256, 0, stream>>>(hs, g2cw, g2cb, dis, w2, N_NODES);
    // c2 = dis * (h2 @ g2bw^T) -> bf16
    mgemm_k<128, 32, 4, 1, 1, 2, 1, false>
        <<<GB, 256, 0, stream>>>(hs, g2bw, nullptr, dis, c2, N_NODES);
    // h = normalize(elu(dis * combine(w2, gather(c2)) + g2_bias))
    gather2_k<<<N_NODES / 4, 256, 0, stream>>>(starts, cnt, srclist, c2, w2, dis, g2b, hout);
    // per-graph pooling + attention heads
    graph_k<<<N_GRAPHS, 128, 0, stream>>>(hout, z_e, aw, ab, fcgw, fcgb, fccgw, fccgb, z_a, z_c);
}

// Round 10
// 294.092 us; speedup vs baseline: 2.2796x; 1.1331x over previous
//
#include <hip/hip_runtime.h>
#include <hip/hip_bf16.h>
#include <math.h>

#define N_NODES  100000
#define N_EDGES  1600000
#define N_GRAPHS 1000
#define NPG      100
#define NBKT     391          // ceil(100000/256); bucket = dst >> 8
#define EPB      4096         // edges per block in binning kernels

typedef float  f32x4 __attribute__((ext_vector_type(4)));
typedef short  s16x8 __attribute__((ext_vector_type(8)));

__device__ __forceinline__ float elu_f(float x) {
    return x > 0.0f ? x : expm1f(x);
}
__device__ __forceinline__ float bf2f(unsigned int u16) {
    union { unsigned int i; float f; } v; v.i = u16 << 16; return v.f;
}
__device__ __forceinline__ unsigned short f2bf(float f) {
    __hip_bfloat16 h = __float2bfloat16(f);
    return *reinterpret_cast<unsigned short*>(&h);
}
__device__ __forceinline__ s16x8 cvt8(const float4& a, const float4& b) {
    s16x8 o;
    o[0]=(short)f2bf(a.x); o[1]=(short)f2bf(a.y); o[2]=(short)f2bf(a.z); o[3]=(short)f2bf(a.w);
    o[4]=(short)f2bf(b.x); o[5]=(short)f2bf(b.y); o[6]=(short)f2bf(b.z); o[7]=(short)f2bf(b.w);
    return o;
}

// ---------------- binned CSR build ----------------
__global__ __launch_bounds__(512) void zero_bkt_k(int* __restrict__ bkt_cnt) {
    int t = threadIdx.x;
    if (t < NBKT) bkt_cnt[t] = 0;
}

__global__ __launch_bounds__(256) void bincount_k(const int* __restrict__ ei, int* __restrict__ bkt_cnt) {
    __shared__ int h[NBKT];
    const int t = threadIdx.x;
    for (int i = t; i < NBKT; i += 256) h[i] = 0;
    __syncthreads();
    const int4* dst4 = (const int4*)(ei + N_EDGES);
    int i0 = blockIdx.x * (EPB / 4);
    for (int i = t; i < EPB / 4; i += 256) {
        int g = i0 + i;
        if (g < N_EDGES / 4) {
            int4 d = dst4[g];
            atomicAdd(&h[d.x >> 8], 1);
            atomicAdd(&h[d.y >> 8], 1);
            atomicAdd(&h[d.z >> 8], 1);
            atomicAdd(&h[d.w >> 8], 1);
        }
    }
    __syncthreads();
    for (int i = t; i < NBKT; i += 256)
        if (h[i]) atomicAdd(&bkt_cnt[i], h[i]);
}

__global__ __launch_bounds__(512) void bkt_scan_k(const int* __restrict__ bkt_cnt,
                                                  int* __restrict__ bkt_start,
                                                  int* __restrict__ bkt_cursor)
{
    __shared__ int s[512];
    int t = threadIdx.x;
    s[t] = (t < NBKT) ? bkt_cnt[t] : 0;
    __syncthreads();
    #pragma unroll
    for (int off = 1; off < 512; off <<= 1) {
        int u = (t >= off) ? s[t - off] : 0;
        __syncthreads();
        s[t] += u;
        __syncthreads();
    }
    if (t <= NBKT) {
        int v = (t == 0) ? 0 : s[t - 1];
        bkt_start[t] = v;
        if (t < NBKT) bkt_cursor[t] = v;
    }
}

__global__ __launch_bounds__(256) void binscatter_k(const int* __restrict__ ei,
                                                    int* __restrict__ bkt_cursor,
                                                    int2* __restrict__ pairs)
{
    __shared__ int h[NBKT];
    __shared__ int base[NBKT];
    const int t = threadIdx.x;
    for (int i = t; i < NBKT; i += 256) h[i] = 0;
    __syncthreads();
    const int4* src4 = (const int4*)ei;
    const int4* dst4 = (const int4*)(ei + N_EDGES);
    int i0 = blockIdx.x * (EPB / 4);
    for (int i = t; i < EPB / 4; i += 256) {
        int g = i0 + i;
        if (g < N_EDGES / 4) {
            int4 d = dst4[g];
            atomicAdd(&h[d.x >> 8], 1);
            atomicAdd(&h[d.y >> 8], 1);
            atomicAdd(&h[d.z >> 8], 1);
            atomicAdd(&h[d.w >> 8], 1);
        }
    }
    __syncthreads();
    for (int i = t; i < NBKT; i += 256) {
        int c = h[i];
        base[i] = c ? atomicAdd(&bkt_cursor[i], c) : 0;
        h[i] = 0;
    }
    __syncthreads();
    for (int i = t; i < EPB / 4; i += 256) {
        int g = i0 + i;
        if (g < N_EDGES / 4) {
            int4 s4 = src4[g];
            int4 d4 = dst4[g];
            int b, r;
            b = d4.x >> 8; r = atomicAdd(&h[b], 1); pairs[base[b] + r] = make_int2(s4.x, d4.x);
            b = d4.y >> 8; r = atomicAdd(&h[b], 1); pairs[base[b] + r] = make_int2(s4.y, d4.y);
            b = d4.z >> 8; r = atomicAdd(&h[b], 1); pairs[base[b] + r] = make_int2(s4.z, d4.z);
            b = d4.w >> 8; r = atomicAdd(&h[b], 1); pairs[base[b] + r] = make_int2(s4.w, d4.w);
        }
    }
}

__global__ __launch_bounds__(256) void bucket_csr_k(const int2* __restrict__ pairs,
                                                    const int* __restrict__ bkt_start,
                                                    int* __restrict__ starts,
                                                    int* __restrict__ cnt,
                                                    float* __restrict__ dis,
                                                    int* __restrict__ srclist)
{
    __shared__ int s[256];
    __shared__ int cur[256];
    const int b = blockIdx.x, t = threadIdx.x;
    const int lo = bkt_start[b], hi = bkt_start[b + 1];
    const int n0 = b << 8;
    const int nn = min(256, N_NODES - n0);

    s[t] = 0;
    __syncthreads();
    for (int i = lo + t; i < hi; i += 256) {
        int2 p = pairs[i];
        atomicAdd(&s[p.y & 255], 1);
    }
    __syncthreads();
    int v = s[t];
    __syncthreads();
    s[t] = v;
    __syncthreads();
    #pragma unroll
    for (int off = 1; off < 256; off <<= 1) {
        int u = (t >= off) ? s[t - off] : 0;
        __syncthreads();
        s[t] += u;
        __syncthreads();
    }
    int ex = lo + s[t] - v;
    if (t < nn) {
        starts[n0 + t] = ex;
        cnt[n0 + t] = v;
        dis[n0 + t] = rsqrtf(1.0f + (float)v);
    }
    cur[t] = ex;
    __syncthreads();
    for (int i = lo + t; i < hi; i += 256) {
        int2 p = pairs[i];
        int pos = atomicAdd(&cur[p.y & 255], 1);
        srclist[pos] = p.x;
    }
}

// ---------------- MFMA GEMM (fused dual-output) ----------------
// A: fp32 (AF32, cvt to bf16) or bf16. W1[N1,K], W2[N2,K] fp32.
// If N2==0: out1[m,n] = bf16(elu(v + bias[n]))            (layer-0 h)
// Else: n<N1: out1[m,n] = bf16(dis[m]*v)                  (c part)
//       n>=N1: out2[m,n-N1] = v + bias[n-N1]  (fp32)      (w part)
template<int K, int N1, int N2, int WR, int WC, int RT, int CT, bool AF32>
__global__ __launch_bounds__(256) void mgemm_k(
    const void* __restrict__ Av, const float* __restrict__ W1,
    const float* __restrict__ W2, const float* __restrict__ bias,
    const float* __restrict__ dis,
    void* __restrict__ out1, float* __restrict__ out2, int M)
{
    constexpr int KT = K / 32;
    const int t = threadIdx.x;
    const int wave = t >> 6, lane = t & 63;
    const int wr = wave / WC, wc = wave % WC;
    const int lr = lane & 15, lk = lane >> 4;
    const int blockRow = blockIdx.x * (WR * RT * 16);

    f32x4 acc[RT][CT];
    #pragma unroll
    for (int rt = 0; rt < RT; ++rt)
        #pragma unroll
        for (int ct = 0; ct < CT; ++ct)
            acc[rt][ct] = (f32x4){0.f, 0.f, 0.f, 0.f};

    const float*          Af = (const float*)Av;
    const unsigned short* Ab = (const unsigned short*)Av;

    #pragma unroll
    for (int kt = 0; kt < KT; ++kt) {
        const int k0 = kt * 32 + lk * 8;
        s16x8 afr[RT];
        #pragma unroll
        for (int rt = 0; rt < RT; ++rt) {
            int r = blockRow + (wr * RT + rt) * 16 + lr;
            r = (r < M) ? r : (M - 1);
            if constexpr (AF32) {
                const float* ap = Af + (size_t)r * K + k0;
                float4 v1 = *(const float4*)ap;
                float4 v2 = *(const float4*)(ap + 4);
                afr[rt] = cvt8(v1, v2);
            } else {
                afr[rt] = *(const s16x8*)(Ab + (size_t)r * K + k0);
            }
        }
        s16x8 bfr[CT];
        #pragma unroll
        for (int ct = 0; ct < CT; ++ct) {
            int n = (wc * CT + ct) * 16 + lr;
            const float* wp = (N2 == 0 || n < N1) ? (W1 + (size_t)n * K + k0)
                                                  : (W2 + (size_t)(n - N1) * K + k0);
            float4 v1 = *(const float4*)wp;
            float4 v2 = *(const float4*)(wp + 4);
            bfr[ct] = cvt8(v1, v2);
        }
        #pragma unroll
        for (int rt = 0; rt < RT; ++rt)
            #pragma unroll
            for (int ct = 0; ct < CT; ++ct)
                acc[rt][ct] = __builtin_amdgcn_mfma_f32_16x16x32_bf16(afr[rt], bfr[ct], acc[rt][ct], 0, 0, 0);
    }

    #pragma unroll
    for (int rt = 0; rt < RT; ++rt) {
        int mbase = blockRow + (wr * RT + rt) * 16 + lk * 4;
        #pragma unroll
        for (int j = 0; j < 4; ++j) {
            int m = mbase + j;
            if (m >= M) continue;
            float dsc = (N2 == 0) ? 1.0f : dis[m];
            #pragma unroll
            for (int ct = 0; ct < CT; ++ct) {
                int n = (wc * CT + ct) * 16 + lr;
                float v = acc[rt][ct][j];
                if constexpr (N2 == 0) {
                    v = elu_f(v + bias[n]);
                    ((unsigned short*)out1)[(size_t)m * N1 + n] = f2bf(v);
                } else {
                    if (n < N1) {
                        ((unsigned short*)out1)[(size_t)m * N1 + n] = f2bf(dsc * v);
                    } else {
                        out2[(size_t)m * N2 + (n - N1)] = v + bias[n - N1];
                    }
                }
            }
        }
    }
}

// ---------------- layer-1 gather (wave/node, 4 edge slots) + combine + elu ----------------
// block = 256 = 4 nodes x 64 threads; lane = slot(4) x featquad(16); h2 out bf16
__global__ __launch_bounds__(256) void gather1_k(
    const int* __restrict__ starts, const int* __restrict__ cnt,
    const int* __restrict__ srclist, const unsigned short* __restrict__ c,
    const float* __restrict__ w1, const float* __restrict__ dis,
    const float* __restrict__ bias, unsigned short* __restrict__ h2b)
{
    __shared__ float aggS[4][68];

    const int t = threadIdx.x;
    const int nn   = t >> 6;
    const int lane = t & 63;
    const int q    = lane & 15;
    const int slot = lane >> 4;
    const int n    = blockIdx.x * 4 + nn;

    const int s0 = starts[n];
    const int cn = cnt[n];
    float a0 = 0.f, a1 = 0.f, a2 = 0.f, a3 = 0.f;
    if (slot == 0) {
        uint2 u = *(const uint2*)(c + (size_t)n * 64 + q * 4);
        a0 = bf2f(u.x & 0xffff); a1 = bf2f(u.x >> 16);
        a2 = bf2f(u.y & 0xffff); a3 = bf2f(u.y >> 16);
    }
    for (int j = slot; j < cn; j += 4) {
        int src = srclist[s0 + j];
        uint2 u = *(const uint2*)(c + (size_t)src * 64 + q * 4);
        a0 += bf2f(u.x & 0xffff); a1 += bf2f(u.x >> 16);
        a2 += bf2f(u.y & 0xffff); a3 += bf2f(u.y >> 16);
    }
    a0 += __shfl_xor(a0, 16, 64); a0 += __shfl_xor(a0, 32, 64);
    a1 += __shfl_xor(a1, 16, 64); a1 += __shfl_xor(a1, 32, 64);
    a2 += __shfl_xor(a2, 16, 64); a2 += __shfl_xor(a2, 32, 64);
    a3 += __shfl_xor(a3, 16, 64); a3 += __shfl_xor(a3, 32, 64);
    if (slot == 0) {
        aggS[nn][q * 4 + 0] = a0;
        aggS[nn][q * 4 + 1] = a1;
        aggS[nn][q * 4 + 2] = a2;
        aggS[nn][q * 4 + 3] = a3;
    }
    __syncthreads();

    const float dn = dis[n];
    const float* wr = w1 + (size_t)n * 32;
    unsigned short* out = h2b + (size_t)n * 128;
    #pragma unroll
    for (int r = 0; r < 2; ++r) {
        int j = r * 64 + lane;
        int hh = j >> 4, f = j & 15;
        float4 wv = *(const float4*)(wr + hh * 4);
        float s = wv.x * aggS[nn][0 * 16 + f] + wv.y * aggS[nn][1 * 16 + f]
                + wv.z * aggS[nn][2 * 16 + f] + wv.w * aggS[nn][3 * 16 + f];
        float v = elu_f(s * dn + bias[j]);
        out[j] = f2bf(v);
    }
}

// ---------------- layer-2 gather (wave/node, 4 edge slots) + combine + elu + L2 norm ----------------
__global__ __launch_bounds__(256) void gather2_k(
    const int* __restrict__ starts, const int* __restrict__ cnt,
    const int* __restrict__ srclist, const unsigned short* __restrict__ c,
    const float* __restrict__ w2, const float* __restrict__ dis,
    const float* __restrict__ bias, float* __restrict__ hout)
{
    __shared__ float aggS[4][36];

    const int t = threadIdx.x;
    const int nn   = t >> 6;
    const int lane = t & 63;
    const int q    = lane & 15;
    const int slot = lane >> 4;
    const int n    = blockIdx.x * 4 + nn;

    const int s0 = starts[n];
    const int cn = cnt[n];
    float a0 = 0.f, a1 = 0.f;
    if (slot == 0) {
        unsigned int u = *(const unsigned int*)(c + (size_t)n * 32 + q * 2);
        a0 = bf2f(u & 0xffff); a1 = bf2f(u >> 16);
    }
    for (int j = slot; j < cn; j += 4) {
        int src = srclist[s0 + j];
        unsigned int u = *(const unsigned int*)(c + (size_t)src * 32 + q * 2);
        a0 += bf2f(u & 0xffff); a1 += bf2f(u >> 16);
    }
    a0 += __shfl_xor(a0, 16, 64); a0 += __shfl_xor(a0, 32, 64);
    a1 += __shfl_xor(a1, 16, 64); a1 += __shfl_xor(a1, 32, 64);
    if (slot == 0) {
        aggS[nn][q * 2 + 0] = a0;
        aggS[nn][q * 2 + 1] = a1;
    }
    __syncthreads();

    const float dn = dis[n];
    const int hh = lane >> 3, f = lane & 7;
    float4 wv = *(const float4*)(w2 + (size_t)n * 32 + hh * 4);
    float s = wv.x * aggS[nn][0 * 8 + f] + wv.y * aggS[nn][1 * 8 + f]
            + wv.z * aggS[nn][2 * 8 + f] + wv.w * aggS[nn][3 * 8 + f];
    float sv = elu_f(s * dn + bias[lane]);

    float tot = sv * sv;
    #pragma unroll
    for (int o = 1; o < 64; o <<= 1) tot += __shfl_xor(tot, o, 64);
    float inv = 1.0f / fmaxf(sqrtf(tot), 1e-12f);
    hout[(size_t)n * 64 + lane] = sv * inv;
}

// ---------------- per-graph tail: z_a, attention softmax, z_c ----------------
__global__ __launch_bounds__(128) void graph_k(const float* __restrict__ h,
                                               const float* __restrict__ z_e,
                                               const float* __restrict__ aw,
                                               const float* __restrict__ ab,
                                               const float* __restrict__ fcgw,
                                               const float* __restrict__ fcgb,
                                               const float* __restrict__ fccgw,
                                               const float* __restrict__ fccgb,
                                               float* __restrict__ z_a,
                                               float* __restrict__ z_c)
{
    __shared__ float Hs[NPG * 64];
    __shared__ float sumh[64], wsh[64], lg[NPG], ex[NPG];
    __shared__ float red[2];
    int g = blockIdx.x, t = threadIdx.x;
    const float* hg = h + (size_t)g * NPG * 64;
    for (int idx = t; idx < NPG * 64; idx += 128) Hs[idx] = hg[idx];
    __syncthreads();

    if (t < 64) {
        float s = 0.0f;
        for (int n = 0; n < NPG; ++n) s += Hs[n * 64 + t];
        sumh[t] = s;
    }
    __syncthreads();

    if (t < 64) {
        float acc = fcgb[t];
        for (int f = 0; f < 64; ++f) acc = fmaf(sumh[f], fcgw[t * 64 + f], acc);
        z_a[(size_t)g * 64 + t] = acc;
    }
    if (t < NPG) {
        float zd = 0.0f;
        for (int q = 0; q < 32; ++q) zd = fmaf(z_e[(size_t)g * 32 + q], aw[64 + q], zd);
        float dot = 0.0f;
        for (int k0 = 0; k0 < 64; ++k0) {
            int k = (k0 + t) & 63;
            dot = fmaf(Hs[t * 64 + k], aw[k], dot);
        }
        lg[t] = dot + zd + ab[0] + 1e-16f;
    }
    __syncthreads();

    if (t < 64) {
        float m = -INFINITY;
        for (int n = t; n < NPG; n += 64) m = fmaxf(m, lg[n]);
        #pragma unroll
        for (int o = 1; o < 64; o <<= 1) m = fmaxf(m, __shfl_xor(m, o, 64));
        if (t == 0) red[0] = m;
    }
    __syncthreads();
    float m = red[0];
    if (t < NPG) ex[t] = expf(lg[t] - m);
    __syncthreads();
    if (t < 64) {
        float s = 0.0f;
        for (int n = t; n < NPG; n += 64) s += ex[n];
        #pragma unroll
        for (int o = 1; o < 64; o <<= 1) s += __shfl_xor(s, o, 64);
        if (t == 0) red[1] = s + 1e-16f;
    }
    __syncthreads();
    float inv_denom = 1.0f / red[1];
    if (t < 64) {
        float a = 0.0f;
        for (int n = 0; n < NPG; ++n) a = fmaf(ex[n], Hs[n * 64 + t], a);
        wsh[t] = a * inv_denom;
    }
    __syncthreads();
    if (t < 64) {
        float acc = fccgb[t];
        for (int f = 0; f < 64; ++f) acc = fmaf(wsh[f], fccgw[t * 64 + f], acc);
        z_c[(size_t)g * 64 + t] = acc;
    }
}

extern "C" void kernel_launch(void* const* d_in, const int* in_sizes, int n_in,
                              void* d_out, int out_size, void* d_ws, size_t ws_size,
                              hipStream_t stream)
{
    const float* x     = (const float*)d_in[0];
    const int*   ei    = (const int*)d_in[1];
    const float* z_e   = (const float*)d_in[4];
    const float* nfc_w = (const float*)d_in[5];
    const float* nfc_b = (const float*)d_in[6];
    const float* g1bw  = (const float*)d_in[7];
    const float* g1cw  = (const float*)d_in[8];
    const float* g1cb  = (const float*)d_in[9];
    const float* g1b   = (const float*)d_in[10];
    const float* g2bw  = (const float*)d_in[11];
    const float* g2cw  = (const float*)d_in[12];
    const float* g2cb  = (const float*)d_in[13];
    const float* g2b   = (const float*)d_in[14];
    const float* aw    = (const float*)d_in[15];
    const float* ab    = (const float*)d_in[16];
    const float* fcgw  = (const float*)d_in[17];
    const float* fcgb  = (const float*)d_in[18];
    const float* fccgw = (const float*)d_in[19];
    const float* fccgb = (const float*)d_in[20];

    // workspace layout (~75 MB)
    float* ws        = (float*)d_ws;
    float* dis       = ws;                           // 102400 fl
    int*   cnt       = (int*)(ws + 102400);          // 102400
    int*   starts    = cnt + 102400;                 // 102400
    int*   bkt_cnt   = starts + 102400;              // 512
    int*   bkt_start = bkt_cnt + 512;                // 512
    int*   bkt_cur   = bkt_start + 512;              // 512
    int*   srclist   = bkt_cur + 512;                // 1,600,000
    float* hbuf      = (float*)(srclist + 1600000);  // 6.4M fl: h bf16 [100k x 128]
    float* c1f       = hbuf + 6400000;               // 3.2M fl: c1 bf16 [100k x 64] / c2 alias
    float* w1        = c1f + 3200000;                // 3.2M fl
    float* w2        = w1 + 3200000;                 // 3.2M fl
    unsigned short* hb = (unsigned short*)hbuf;      // h (bf16)
    unsigned short* c1 = (unsigned short*)c1f;
    unsigned short* c2 = (unsigned short*)c1f;       // c1 dead before c2 written
    int2*  pairs     = (int2*)hbuf;                  // 12.8MB ≤ 25.6MB region, dead before hb

    float* z_a  = (float*)d_out;
    float* z_c  = z_a + (size_t)N_GRAPHS * 64;
    float* hout = z_a + (size_t)2 * N_GRAPHS * 64;

    const int GB = (N_NODES + 63) / 64;   // 1563 blocks of 64 rows

    // binned CSR build
    zero_bkt_k<<<1, 512, 0, stream>>>(bkt_cnt);
    bincount_k<<<(N_EDGES + EPB - 1) / EPB, 256, 0, stream>>>(ei, bkt_cnt);
    bkt_scan_k<<<1, 512, 0, stream>>>(bkt_cnt, bkt_start, bkt_cur);
    binscatter_k<<<(N_EDGES + EPB - 1) / EPB, 256, 0, stream>>>(ei, bkt_cur, pairs);
    bucket_csr_k<<<NBKT, 256, 0, stream>>>(pairs, bkt_start, starts, cnt, dis, srclist);

    // h1 = elu(x @ nfc_w^T + b) -> bf16                  [100k,64]x[64,128]
    mgemm_k<64, 128, 0, 2, 2, 2, 4, true>
        <<<GB, 256, 0, stream>>>(x, nfc_w, nullptr, nfc_b, dis, hb, nullptr, N_NODES);
    // fused: c1 = dis*(h1@g1bw^T) bf16 ; w1 = h1@g1cw^T + g1cb fp32   [100k,128]x[128,96]
    mgemm_k<128, 64, 32, 2, 2, 2, 3, false>
        <<<GB, 256, 0, stream>>>(hb, g1bw, g1cw, g1cb, dis, c1, w1, N_NODES);
    // h2 = elu(dis * combine(w1, gather(c1)) + g1_bias) -> bf16 (hb)
    gather1_k<<<N_NODES / 4, 256, 0, stream>>>(starts, cnt, srclist, c1, w1, dis, g1b, hb);
    // fused: c2 = dis*(h2@g2bw^T) bf16 ; w2 = h2@g2cw^T + g2cb fp32   [100k,128]x[128,64]
    mgemm_k<128, 32, 32, 2, 2, 2, 2, false>
        <<<GB, 256, 0, stream>>>(hb, g2bw, g2cw, g2cb, dis, c2, w2, N_NODES);
    // h = normalize(elu(dis * combine(w2, gather(c2)) + g2_bias))
    gather2_k<<<N_NODES / 4, 256, 0, stream>>>(starts, cnt, srclist, c2, w2, dis, g2b, hout);
    // per-graph pooling + attention heads
    graph_k<<<N_GRAPHS, 128, 0, stream>>>(hout, z_e, aw, ab, fcgw, fcgb, fccgw, fccgb, z_a, z_c);
}